// Round 6
// baseline (301.327 us; speedup 1.0000x reference)
//
#include <hip/hip_runtime.h>

#define FDIM 128

typedef __attribute__((ext_vector_type(8))) short bf16x8;
typedef __attribute__((ext_vector_type(4))) float f32x4;

// Column permutation for internal Z/S storage (within a 128-col half):
//   orig c: ct=c>>4, n=c&15  ->  stored s = 64*(ct>=4) + n*4 + (ct&3)
//   inv:    hi=s>>6, s6=s&63, n=s6>>2, ctl=s6&3 -> c = (ctl+4*hi)*16 + n

__device__ __forceinline__ unsigned short f2bf(float f){
  unsigned int u = __float_as_uint(f);
  unsigned int r = u + 0x7FFFu + ((u >> 16) & 1u);
  return (unsigned short)(r >> 16);
}

// ---------------- init: zero cnt, zero dummy Z/Z2 rows, build Wcat ----------------
__global__ void k_init(const float* __restrict__ Wl0, const float* __restrict__ Wr0,
                       const float* __restrict__ Wl1, const float* __restrict__ Wr1,
                       unsigned short* __restrict__ Wcat, int* __restrict__ cnt,
                       unsigned short* __restrict__ Zdummy, unsigned short* __restrict__ Z2dummy,
                       int N, int nb){
  int b = blockIdx.x;
  if (b < nb){
    int i = b*256 + threadIdx.x;
    if (i < N) cnt[i] = 0;
    if (b == 0 && threadIdx.x < FDIM){
      Zdummy[threadIdx.x]  = 0;
      Z2dummy[threadIdx.x] = 0;
    }
  } else {
    int i = (b - nb)*256 + threadIdx.x;     // 0 .. 65535
    int l   = i >> 15;
    int rem = i & 32767;
    int row = rem >> 7, k = rem & 127;
    int ksrc = k;
    if (l == 1){
      int hi = k >> 6, s6 = k & 63;
      ksrc = ((s6 & 3) + 4*hi)*16 + (s6 >> 2);   // invPerm(k)
    }
    const float* W = (l == 0) ? ((row < 128) ? Wl0 : Wr0)
                              : ((row < 128) ? Wl1 : Wr1);
    Wcat[i] = f2bf(W[(row & 127)*128 + ksrc]);
  }
}

// ---------------- degree ----------------
__global__ void k_degree(const int* __restrict__ dst, int* __restrict__ cnt, int E){
  int e = blockIdx.x*256 + threadIdx.x;
  if (e < E) atomicAdd(&cnt[dst[e]], 1);
}

// ---------------- hierarchical scan over PADDED degrees (R5-proven) ----------------
__global__ void k_scan_blocks(const int* __restrict__ cnt, int* __restrict__ excl,
                              int* __restrict__ partials, int N){
  __shared__ int s[256];
  int tid = threadIdx.x;
  int i = blockIdx.x*256 + tid;
  int v = (i < N) ? ((cnt[i] + 7) & ~7) : 0;
  s[tid] = v; __syncthreads();
  for (int off = 1; off < 256; off <<= 1){
    int t = (tid >= off) ? s[tid - off] : 0;
    __syncthreads();
    s[tid] += t;
    __syncthreads();
  }
  if (i < N) excl[i] = s[tid] - v;
  if (tid == 255) partials[blockIdx.x] = s[255];
}

__global__ void k_scan_partials(int* __restrict__ partials, int nb){
  __shared__ int s[512];
  int tid = threadIdx.x;
  int v = (tid < nb) ? partials[tid] : 0;
  s[tid] = v; __syncthreads();
  for (int off = 1; off < 512; off <<= 1){
    int t = (tid >= off) ? s[tid - off] : 0;
    __syncthreads();
    s[tid] += t;
    __syncthreads();
  }
  if (tid < nb) partials[tid] = s[tid] - v;
}

// finalize + pad fused (pad writes slots >= deg, fill writes < deg: disjoint,
// so padding can happen before k_fill)
__global__ void k_finalize_pad(int* __restrict__ row_off, const int* __restrict__ partials,
                               int* __restrict__ cursor, const int* __restrict__ cnt,
                               int* __restrict__ csr_src, int N){
  int i = blockIdx.x*256 + threadIdx.x;
  if (i >= N) return;
  int ro = row_off[i] + partials[blockIdx.x];
  row_off[i] = ro;
  cursor[i]  = ro;
  int d  = cnt[i];
  int pd = (d + 7) & ~7;
  for (int p = d; p < pd; p++) csr_src[ro + p] = N;
}

// ---------------- fill ----------------
__global__ void k_fill(const int* __restrict__ src, const int* __restrict__ dst,
                       int* __restrict__ cursor, int* __restrict__ csr_src, int E){
  int e = blockIdx.x*256 + threadIdx.x;
  if (e >= E) return;
  int d = dst[e];
  int pos = atomicAdd(&cursor[d], 1);
  csr_src[pos] = src[e];
}

// ---------------- layer-1 dual GEMM: Z = X@Wl^T, S = X@Wr^T + (bl+br) ----------------
// fp32 A input, permuted-col bf16 output. Register-prefetch pipelined (R5).
// R0-proven config: grid 512, (256,2).
__global__ __launch_bounds__(256, 2)
void k_dualgemm1(const float* __restrict__ X, const unsigned short* __restrict__ Wcat,
                 const float* __restrict__ bl, const float* __restrict__ br,
                 unsigned short* __restrict__ Z, unsigned short* __restrict__ S,
                 int N, int nrb){
  __shared__ unsigned short lds[64*FDIM];
  const int tid  = threadIdx.x;
  const int wave = tid >> 6;
  const int lane = tid & 63;
  const int n = lane & 15, q = lane >> 4;

  float bias[4];
#pragma unroll
  for (int ctl = 0; ctl < 4; ctl++){
    int ct = wave*4 + ctl;
    if (ct >= 8){ int col = (ct - 8)*16 + n; bias[ctl] = bl[col] + br[col]; }
    else bias[ctl] = 0.0f;
  }

  float4 pf[8];
  const int r_   = tid >> 4;
  const int c16_ = tid & 15;

  auto issue_load = [&](int rb){
    int row0 = rb*64;
#pragma unroll
    for (int it = 0; it < 4; it++){
      int r  = r_ + it*16;
      int gr = row0 + r;
      if (gr < N){
        const float4* sp = (const float4*)(X + (size_t)gr*FDIM + c16_*8);
        pf[2*it]   = sp[0];
        pf[2*it+1] = sp[1];
      } else {
        pf[2*it]   = make_float4(0,0,0,0);
        pf[2*it+1] = make_float4(0,0,0,0);
      }
    }
  };

  int rb = blockIdx.x;
  if (rb < nrb) issue_load(rb);

  for (; rb < nrb; rb += gridDim.x){
    int row0 = rb*64;
    __syncthreads();
#pragma unroll
    for (int it = 0; it < 4; it++){
      int r = r_ + it*16;
      float4 v0 = pf[2*it], v1 = pf[2*it+1];
      bf16x8 p;
      p[0] = (short)f2bf(v0.x); p[1] = (short)f2bf(v0.y);
      p[2] = (short)f2bf(v0.z); p[3] = (short)f2bf(v0.w);
      p[4] = (short)f2bf(v1.x); p[5] = (short)f2bf(v1.y);
      p[6] = (short)f2bf(v1.z); p[7] = (short)f2bf(v1.w);
      *(bf16x8*)(lds + r*FDIM + ((c16_ ^ (r & 15)) * 8)) = p;
    }
    __syncthreads();

    int rbn = rb + gridDim.x;
    if (rbn < nrb) issue_load(rbn);

    f32x4 acc[4][4];
#pragma unroll
    for (int rt = 0; rt < 4; rt++)
#pragma unroll
      for (int ctl = 0; ctl < 4; ctl++)
        acc[rt][ctl] = (f32x4){0.f, 0.f, 0.f, 0.f};

#pragma unroll
    for (int kk = 0; kk < 4; kk++){
      bf16x8 bfr[4];
#pragma unroll
      for (int ctl = 0; ctl < 4; ctl++){
        int row = (wave*4 + ctl)*16 + n;
        bfr[ctl] = *(const bf16x8*)(Wcat + row*FDIM + kk*32 + q*8);
      }
      bf16x8 afr[4];
#pragma unroll
      for (int rt = 0; rt < 4; rt++){
        int r = rt*16 + n;
        int c16 = (kk*4 + q) ^ n;
        afr[rt] = *(const bf16x8*)(lds + r*FDIM + c16*8);
      }
#pragma unroll
      for (int rt = 0; rt < 4; rt++)
#pragma unroll
        for (int ctl = 0; ctl < 4; ctl++)
          acc[rt][ctl] = __builtin_amdgcn_mfma_f32_16x16x32_bf16(
              afr[rt], bfr[ctl], acc[rt][ctl], 0, 0, 0);
    }

    unsigned short* dstb = (wave < 2) ? Z : S;
    int s0 = 64*(wave & 1) + n*4;
#pragma unroll
    for (int rt = 0; rt < 4; rt++){
#pragma unroll
      for (int r = 0; r < 4; r++){
        int grow = row0 + rt*16 + q*4 + r;
        if (grow < N){
          float v0 = acc[rt][0][r] + bias[0];
          float v1 = acc[rt][1][r] + bias[1];
          float v2 = acc[rt][2][r] + bias[2];
          float v3 = acc[rt][3][r] + bias[3];
          uint2 u;
          u.x = ((unsigned)f2bf(v1) << 16) | (unsigned)f2bf(v0);
          u.y = ((unsigned)f2bf(v3) << 16) | (unsigned)f2bf(v2);
          *(uint2*)(dstb + (size_t)grow*FDIM + s0) = u;
        }
      }
    }
  }
}

// ---------------- fused layer-1 aggregate + layer-2 dual GEMM ----------------
// R6-R10 occupancy study: launch geometry cannot raise residency past ~2
// blocks/CU without a VGPR clamp that spills. Reverted to R0-proven grid 512.
// R11: per-lane MLP is the lever instead — 16 gathers in flight (was 8),
// clamp-free batches (pad slots point at dummy row N, which is all zeros, so
// out-of-range edges contribute 0 and need no branches).
__global__ __launch_bounds__(256)
void k_agg_gemm(const unsigned short* __restrict__ Z, unsigned short* __restrict__ S,
                const int* __restrict__ row_off, const int* __restrict__ cnt,
                const int* __restrict__ csr_src,
                const unsigned short* __restrict__ Wcat,
                const float* __restrict__ bl, const float* __restrict__ br,
                unsigned short* __restrict__ Z2, int N, int nrb){
  __shared__ unsigned short lds[64*FDIM];
  const int tid  = threadIdx.x;
  const int wave = tid >> 6;
  const int lane = tid & 63;
  const int n = lane & 15, q = lane >> 4;
  const int g16   = lane & 15;   // pos within 16-lane row-group == 16B chunk idx
  const int gbase = lane & 48;   // first lane of this row-group

  float bias[4];
#pragma unroll
  for (int ctl = 0; ctl < 4; ctl++){
    int ct = wave*4 + ctl;
    if (ct >= 8){ int col = (ct - 8)*16 + n; bias[ctl] = bl[col] + br[col]; }
    else bias[ctl] = 0.0f;
  }

  for (int rb = blockIdx.x; rb < nrb; rb += gridDim.x){
    int row0 = rb*64;
    __syncthreads();
    // ---- staging: build h rows (layer-1 aggregate, permuted space) ----
#pragma unroll
    for (int it = 0; it < 4; it++){
      int r  = (tid >> 4) + it*16;
      int gr = row0 + r;
      bf16x8 p;
      if (gr < N){
        int ro   = row_off[gr];
        int deg  = cnt[gr];
        int pdeg = (deg + 7) & ~7;
        float inv = 1.0f / (float)(deg > 1 ? deg : 1);
        float hacc[8];
#pragma unroll
        for (int z = 0; z < 8; z++) hacc[z] = 0.f;
        for (int base = 0; base < pdeg; base += 16){
          // slots >= pdeg-base use dummy node N (zero row) -> no clamps below
          int sidx = (g16 < pdeg - base) ? csr_src[ro + base + g16] : N;
          int id[16];
#pragma unroll
          for (int t = 0; t < 16; t++) id[t] = __shfl(sidx, gbase + t);
          uint4 v[16];                        // 16 gathers in flight
#pragma unroll
          for (int t = 0; t < 16; t++)
            v[t] = *(const uint4*)(Z + (size_t)(unsigned)id[t]*FDIM + g16*8);
#pragma unroll
          for (int t = 0; t < 16; t++){
            hacc[0] += __uint_as_float(v[t].x << 16);
            hacc[1] += __uint_as_float(v[t].x & 0xFFFF0000u);
            hacc[2] += __uint_as_float(v[t].y << 16);
            hacc[3] += __uint_as_float(v[t].y & 0xFFFF0000u);
            hacc[4] += __uint_as_float(v[t].z << 16);
            hacc[5] += __uint_as_float(v[t].z & 0xFFFF0000u);
            hacc[6] += __uint_as_float(v[t].w << 16);
            hacc[7] += __uint_as_float(v[t].w & 0xFFFF0000u);
          }
        }
        uint4 sv = *(const uint4*)(S + (size_t)gr*FDIM + g16*8);
        float s0 = __uint_as_float(sv.x << 16), s1 = __uint_as_float(sv.x & 0xFFFF0000u);
        float s2 = __uint_as_float(sv.y << 16), s3 = __uint_as_float(sv.y & 0xFFFF0000u);
        float s4 = __uint_as_float(sv.z << 16), s5 = __uint_as_float(sv.z & 0xFFFF0000u);
        float s6 = __uint_as_float(sv.w << 16), s7 = __uint_as_float(sv.w & 0xFFFF0000u);
        p[0] = (short)f2bf(fmaxf(hacc[0]*inv + s0, 0.f));
        p[1] = (short)f2bf(fmaxf(hacc[1]*inv + s1, 0.f));
        p[2] = (short)f2bf(fmaxf(hacc[2]*inv + s2, 0.f));
        p[3] = (short)f2bf(fmaxf(hacc[3]*inv + s3, 0.f));
        p[4] = (short)f2bf(fmaxf(hacc[4]*inv + s4, 0.f));
        p[5] = (short)f2bf(fmaxf(hacc[5]*inv + s5, 0.f));
        p[6] = (short)f2bf(fmaxf(hacc[6]*inv + s6, 0.f));
        p[7] = (short)f2bf(fmaxf(hacc[7]*inv + s7, 0.f));
      } else {
#pragma unroll
        for (int z = 0; z < 8; z++) p[z] = 0;
      }
      *(bf16x8*)(lds + r*FDIM + ((g16 ^ (r & 15)) * 8)) = p;
    }
    __syncthreads();

    // ---- MFMA with layer-2 weights ----
    f32x4 acc[4][4];
#pragma unroll
    for (int rt = 0; rt < 4; rt++)
#pragma unroll
      for (int ctl = 0; ctl < 4; ctl++)
        acc[rt][ctl] = (f32x4){0.f, 0.f, 0.f, 0.f};

#pragma unroll
    for (int kk = 0; kk < 4; kk++){
      bf16x8 bfr[4];
#pragma unroll
      for (int ctl = 0; ctl < 4; ctl++){
        int row = (wave*4 + ctl)*16 + n;
        bfr[ctl] = *(const bf16x8*)(Wcat + row*FDIM + kk*32 + q*8);
      }
      bf16x8 afr[4];
#pragma unroll
      for (int rt = 0; rt < 4; rt++){
        int r = rt*16 + n;
        int c16 = (kk*4 + q) ^ n;
        afr[rt] = *(const bf16x8*)(lds + r*FDIM + c16*8);
      }
#pragma unroll
      for (int rt = 0; rt < 4; rt++)
#pragma unroll
        for (int ctl = 0; ctl < 4; ctl++)
          acc[rt][ctl] = __builtin_amdgcn_mfma_f32_16x16x32_bf16(
              afr[rt], bfr[ctl], acc[rt][ctl], 0, 0, 0);
    }

    // ---- epilogue: Z2 / S (in place) ----
    unsigned short* dstb = (wave < 2) ? Z2 : S;
    int s0c = 64*(wave & 1) + n*4;
#pragma unroll
    for (int rt = 0; rt < 4; rt++){
#pragma unroll
      for (int r = 0; r < 4; r++){
        int grow = row0 + rt*16 + q*4 + r;
        if (grow < N){
          float v0 = acc[rt][0][r] + bias[0];
          float v1 = acc[rt][1][r] + bias[1];
          float v2 = acc[rt][2][r] + bias[2];
          float v3 = acc[rt][3][r] + bias[3];
          uint2 u;
          u.x = ((unsigned)f2bf(v1) << 16) | (unsigned)f2bf(v0);
          u.y = ((unsigned)f2bf(v3) << 16) | (unsigned)f2bf(v2);
          *(uint2*)(dstb + (size_t)grow*FDIM + s0c) = u;
        }
      }
    }
  }
}

// ---------------- final aggregate: out = relu(sum(Z2[src])/deg + S) ----------------
// R9 shape + R11 deep-MLP staging (16 gathers in flight, clamp-free).
__global__ __launch_bounds__(256)
void k_aggregate(const unsigned short* __restrict__ Z2, const unsigned short* __restrict__ S,
                 const int* __restrict__ row_off, const int* __restrict__ cnt,
                 const int* __restrict__ csr_src, float* __restrict__ Out, int N, int nrb){
  __shared__ __align__(16) float lds_out[64*132];   // +4 pad per row vs 128
  const int tid   = threadIdx.x;
  const int lane  = tid & 63;
  const int g16   = lane & 15;
  const int gbase = lane & 48;

  for (int rb = blockIdx.x; rb < nrb; rb += gridDim.x){
    int row0 = rb*64;
    __syncthreads();   // protect lds_out against previous iteration's readers
#pragma unroll
    for (int it = 0; it < 4; it++){
      int r  = (tid >> 4) + it*16;
      int gr = row0 + r;
      if (gr < N){
        int ro   = row_off[gr];
        int deg  = cnt[gr];
        int pdeg = (deg + 7) & ~7;
        float inv = 1.0f / (float)(deg > 1 ? deg : 1);
        float hacc[8];
#pragma unroll
        for (int z = 0; z < 8; z++) hacc[z] = 0.f;
        for (int base = 0; base < pdeg; base += 16){
          int sidx = (g16 < pdeg - base) ? csr_src[ro + base + g16] : N;
          int id[16];
#pragma unroll
          for (int t = 0; t < 16; t++) id[t] = __shfl(sidx, gbase + t);
          uint4 v[16];                        // 16 gathers in flight
#pragma unroll
          for (int t = 0; t < 16; t++)
            v[t] = *(const uint4*)(Z2 + (size_t)(unsigned)id[t]*FDIM + g16*8);
#pragma unroll
          for (int t = 0; t < 16; t++){
            hacc[0] += __uint_as_float(v[t].x << 16);
            hacc[1] += __uint_as_float(v[t].x & 0xFFFF0000u);
            hacc[2] += __uint_as_float(v[t].y << 16);
            hacc[3] += __uint_as_float(v[t].y & 0xFFFF0000u);
            hacc[4] += __uint_as_float(v[t].z << 16);
            hacc[5] += __uint_as_float(v[t].z & 0xFFFF0000u);
            hacc[6] += __uint_as_float(v[t].w << 16);
            hacc[7] += __uint_as_float(v[t].w & 0xFFFF0000u);
          }
        }
        uint4 sv = *(const uint4*)(S + (size_t)gr*FDIM + g16*8);
        float s0 = __uint_as_float(sv.x << 16), s1 = __uint_as_float(sv.x & 0xFFFF0000u);
        float s2 = __uint_as_float(sv.y << 16), s3 = __uint_as_float(sv.y & 0xFFFF0000u);
        float s4 = __uint_as_float(sv.z << 16), s5 = __uint_as_float(sv.z & 0xFFFF0000u);
        float s6 = __uint_as_float(sv.w << 16), s7 = __uint_as_float(sv.w & 0xFFFF0000u);
        float o[8];
        o[0] = fmaxf(hacc[0]*inv + s0, 0.f);
        o[1] = fmaxf(hacc[1]*inv + s1, 0.f);
        o[2] = fmaxf(hacc[2]*inv + s2, 0.f);
        o[3] = fmaxf(hacc[3]*inv + s3, 0.f);
        o[4] = fmaxf(hacc[4]*inv + s4, 0.f);
        o[5] = fmaxf(hacc[5]*inv + s5, 0.f);
        o[6] = fmaxf(hacc[6]*inv + s6, 0.f);
        o[7] = fmaxf(hacc[7]*inv + s7, 0.f);
        // un-permute into LDS: stored s -> orig c
#pragma unroll
        for (int z = 0; z < 8; z++){
          int s_ = g16*8 + z;
          int hi = s_ >> 6, s6i = s_ & 63;
          int c = ((s6i & 3) + 4*hi)*16 + (s6i >> 2);
          lds_out[r*132 + c] = o[z];
        }
      }
    }
    __syncthreads();
    // coalesced float4 write-out
#pragma unroll
    for (int it2 = 0; it2 < 8; it2++){
      int r2  = (tid >> 5) + it2*8;
      int c4  = tid & 31;
      int gr2 = row0 + r2;
      if (gr2 < N){
        *(float4*)(Out + (size_t)gr2*FDIM + c4*4) =
            *(const float4*)(lds_out + r2*132 + c4*4);
      }
    }
  }
}

extern "C" void kernel_launch(void* const* d_in, const int* in_sizes, int n_in,
                              void* d_out, int out_size, void* d_ws, size_t ws_size,
                              hipStream_t stream){
  const float* x   = (const float*)d_in[0];
  const int*   eix = (const int*)d_in[1];
  const float* Wl0 = (const float*)d_in[2];
  const float* bl0 = (const float*)d_in[3];
  const float* Wr0 = (const float*)d_in[4];
  const float* br0 = (const float*)d_in[5];
  const float* Wl1 = (const float*)d_in[6];
  const float* bl1 = (const float*)d_in[7];
  const float* Wr1 = (const float*)d_in[8];
  const float* br1 = (const float*)d_in[9];
  float* out = (float*)d_out;

  int N = in_sizes[0] / FDIM;
  int E = in_sizes[1] / 2;
  const int* src = eix;
  const int* dst = eix + E;

  // workspace (Z and Z2 have N+1 rows: row N is the zero dummy row)
  unsigned short* Z    = (unsigned short*)d_ws;
  unsigned short* Z2   = Z  + (size_t)(N + 1)*FDIM;
  unsigned short* S    = Z2 + (size_t)(N + 1)*FDIM;
  unsigned short* Wcat = S  + (size_t)N*FDIM;
  int* cnt     = (int*)(Wcat + 2*256*128);
  int* row_off = cnt + N;
  int* cursor  = row_off + N;
  int* csr_src = cursor + N;                 // capacity: E + 7N (padding bound)
  int* partials= csr_src + (E + 7*N);

  int nb = (N + 255)/256;

  k_init         <<<nb + 256, 256, 0, stream>>>(Wl0, Wr0, Wl1, Wr1, Wcat, cnt,
                                                Z + (size_t)N*FDIM, Z2 + (size_t)N*FDIM, N, nb);
  k_degree       <<<(E + 255)/256, 256, 0, stream>>>(dst, cnt, E);
  k_scan_blocks  <<<nb, 256, 0, stream>>>(cnt, row_off, partials, N);
  k_scan_partials<<<1, 512, 0, stream>>>(partials, nb);
  k_finalize_pad <<<nb, 256, 0, stream>>>(row_off, partials, cursor, cnt, csr_src, N);
  k_fill         <<<(E + 255)/256, 256, 0, stream>>>(src, dst, cursor, csr_src, E);

  int nrb = (N + 63)/64;
  k_dualgemm1<<<512, 256, 0, stream>>>(x, Wcat, bl0, br0, Z, S, N, nrb);
  k_agg_gemm <<<512, 256, 0, stream>>>(Z, S, row_off, cnt, csr_src,
                                       Wcat + 256*128, bl1, br1, Z2, N, nrb);
  k_aggregate<<<1024, 256, 0, stream>>>(Z2, S, row_off, cnt, csr_src, out, N, nrb);
}

// Round 7
// 292.399 us; speedup vs baseline: 1.0305x; 1.0305x over previous
//
#include <hip/hip_runtime.h>

#define FDIM 128

typedef __attribute__((ext_vector_type(8))) short bf16x8;
typedef __attribute__((ext_vector_type(4))) float f32x4;
typedef __attribute__((ext_vector_type(4))) unsigned int u32x4;
typedef __attribute__((ext_vector_type(2))) unsigned int u32x2;

// Column permutation for internal Z/S storage (within a 128-col half):
//   orig c: ct=c>>4, n=c&15  ->  stored s = 64*(ct>=4) + n*4 + (ct&3)
//   inv:    hi=s>>6, s6=s&63, n=s6>>2, ctl=s6&3 -> c = (ctl+4*hi)*16 + n

__device__ __forceinline__ unsigned short f2bf(float f){
  unsigned int u = __float_as_uint(f);
  unsigned int r = u + 0x7FFFu + ((u >> 16) & 1u);
  return (unsigned short)(r >> 16);
}

// ---------------- init: zero cnt, zero dummy Z/Z2 rows, build Wcat ----------------
__global__ void k_init(const float* __restrict__ Wl0, const float* __restrict__ Wr0,
                       const float* __restrict__ Wl1, const float* __restrict__ Wr1,
                       unsigned short* __restrict__ Wcat, int* __restrict__ cnt,
                       unsigned short* __restrict__ Zdummy, unsigned short* __restrict__ Z2dummy,
                       int N, int nb){
  int b = blockIdx.x;
  if (b < nb){
    int i = b*256 + threadIdx.x;
    if (i < N) cnt[i] = 0;
    if (b == 0 && threadIdx.x < FDIM){
      Zdummy[threadIdx.x]  = 0;
      Z2dummy[threadIdx.x] = 0;
    }
  } else {
    int i = (b - nb)*256 + threadIdx.x;     // 0 .. 65535
    int l   = i >> 15;
    int rem = i & 32767;
    int row = rem >> 7, k = rem & 127;
    int ksrc = k;
    if (l == 1){
      int hi = k >> 6, s6 = k & 63;
      ksrc = ((s6 & 3) + 4*hi)*16 + (s6 >> 2);   // invPerm(k)
    }
    const float* W = (l == 0) ? ((row < 128) ? Wl0 : Wr0)
                              : ((row < 128) ? Wl1 : Wr1);
    Wcat[i] = f2bf(W[(row & 127)*128 + ksrc]);
  }
}

// ---------------- degree ----------------
__global__ void k_degree(const int* __restrict__ dst, int* __restrict__ cnt, int E){
  int e = blockIdx.x*256 + threadIdx.x;
  if (e < E) atomicAdd(&cnt[dst[e]], 1);
}

// ---------------- hierarchical scan over PADDED degrees (R5-proven) ----------------
__global__ void k_scan_blocks(const int* __restrict__ cnt, int* __restrict__ excl,
                              int* __restrict__ partials, int N){
  __shared__ int s[256];
  int tid = threadIdx.x;
  int i = blockIdx.x*256 + tid;
  int v = (i < N) ? ((cnt[i] + 7) & ~7) : 0;
  s[tid] = v; __syncthreads();
  for (int off = 1; off < 256; off <<= 1){
    int t = (tid >= off) ? s[tid - off] : 0;
    __syncthreads();
    s[tid] += t;
    __syncthreads();
  }
  if (i < N) excl[i] = s[tid] - v;
  if (tid == 255) partials[blockIdx.x] = s[255];
}

__global__ void k_scan_partials(int* __restrict__ partials, int nb){
  __shared__ int s[512];
  int tid = threadIdx.x;
  int v = (tid < nb) ? partials[tid] : 0;
  s[tid] = v; __syncthreads();
  for (int off = 1; off < 512; off <<= 1){
    int t = (tid >= off) ? s[tid - off] : 0;
    __syncthreads();
    s[tid] += t;
    __syncthreads();
  }
  if (tid < nb) partials[tid] = s[tid] - v;
}

// finalize + pad fused (pad writes slots >= deg, fill writes < deg: disjoint,
// so padding can happen before k_fill)
__global__ void k_finalize_pad(int* __restrict__ row_off, const int* __restrict__ partials,
                               int* __restrict__ cursor, const int* __restrict__ cnt,
                               int* __restrict__ csr_src, int N){
  int i = blockIdx.x*256 + threadIdx.x;
  if (i >= N) return;
  int ro = row_off[i] + partials[blockIdx.x];
  row_off[i] = ro;
  cursor[i]  = ro;
  int d  = cnt[i];
  int pd = (d + 7) & ~7;
  for (int p = d; p < pd; p++) csr_src[ro + p] = N;
}

// ---------------- fill ----------------
__global__ void k_fill(const int* __restrict__ src, const int* __restrict__ dst,
                       int* __restrict__ cursor, int* __restrict__ csr_src, int E){
  int e = blockIdx.x*256 + threadIdx.x;
  if (e >= E) return;
  int d = dst[e];
  int pos = atomicAdd(&cursor[d], 1);
  csr_src[pos] = src[e];
}

// ---------------- layer-1 dual GEMM: Z = X@Wl^T, S = X@Wr^T + (bl+br) ----------------
// fp32 A input, permuted-col bf16 output. Register-prefetch pipelined (R5).
// R0-proven config: grid 512, (256,2).
// R12 cache hygiene: X is read-once -> NT loads; S stream -> NT stores;
// Z stores stay cached (k_agg_gemm gathers Z next, 6x reuse).
__global__ __launch_bounds__(256, 2)
void k_dualgemm1(const float* __restrict__ X, const unsigned short* __restrict__ Wcat,
                 const float* __restrict__ bl, const float* __restrict__ br,
                 unsigned short* __restrict__ Z, unsigned short* __restrict__ S,
                 int N, int nrb){
  __shared__ unsigned short lds[64*FDIM];
  const int tid  = threadIdx.x;
  const int wave = tid >> 6;
  const int lane = tid & 63;
  const int n = lane & 15, q = lane >> 4;

  float bias[4];
#pragma unroll
  for (int ctl = 0; ctl < 4; ctl++){
    int ct = wave*4 + ctl;
    if (ct >= 8){ int col = (ct - 8)*16 + n; bias[ctl] = bl[col] + br[col]; }
    else bias[ctl] = 0.0f;
  }

  f32x4 pf[8];
  const int r_   = tid >> 4;
  const int c16_ = tid & 15;

  auto issue_load = [&](int rb){
    int row0 = rb*64;
#pragma unroll
    for (int it = 0; it < 4; it++){
      int r  = r_ + it*16;
      int gr = row0 + r;
      if (gr < N){
        const f32x4* sp = (const f32x4*)(X + (size_t)gr*FDIM + c16_*8);
        pf[2*it]   = __builtin_nontemporal_load(sp);
        pf[2*it+1] = __builtin_nontemporal_load(sp + 1);
      } else {
        pf[2*it]   = (f32x4){0.f,0.f,0.f,0.f};
        pf[2*it+1] = (f32x4){0.f,0.f,0.f,0.f};
      }
    }
  };

  int rb = blockIdx.x;
  if (rb < nrb) issue_load(rb);

  for (; rb < nrb; rb += gridDim.x){
    int row0 = rb*64;
    __syncthreads();
#pragma unroll
    for (int it = 0; it < 4; it++){
      int r = r_ + it*16;
      f32x4 v0 = pf[2*it], v1 = pf[2*it+1];
      bf16x8 p;
      p[0] = (short)f2bf(v0[0]); p[1] = (short)f2bf(v0[1]);
      p[2] = (short)f2bf(v0[2]); p[3] = (short)f2bf(v0[3]);
      p[4] = (short)f2bf(v1[0]); p[5] = (short)f2bf(v1[1]);
      p[6] = (short)f2bf(v1[2]); p[7] = (short)f2bf(v1[3]);
      *(bf16x8*)(lds + r*FDIM + ((c16_ ^ (r & 15)) * 8)) = p;
    }
    __syncthreads();

    int rbn = rb + gridDim.x;
    if (rbn < nrb) issue_load(rbn);

    f32x4 acc[4][4];
#pragma unroll
    for (int rt = 0; rt < 4; rt++)
#pragma unroll
      for (int ctl = 0; ctl < 4; ctl++)
        acc[rt][ctl] = (f32x4){0.f, 0.f, 0.f, 0.f};

#pragma unroll
    for (int kk = 0; kk < 4; kk++){
      bf16x8 bfr[4];
#pragma unroll
      for (int ctl = 0; ctl < 4; ctl++){
        int row = (wave*4 + ctl)*16 + n;
        bfr[ctl] = *(const bf16x8*)(Wcat + row*FDIM + kk*32 + q*8);
      }
      bf16x8 afr[4];
#pragma unroll
      for (int rt = 0; rt < 4; rt++){
        int r = rt*16 + n;
        int c16 = (kk*4 + q) ^ n;
        afr[rt] = *(const bf16x8*)(lds + r*FDIM + c16*8);
      }
#pragma unroll
      for (int rt = 0; rt < 4; rt++)
#pragma unroll
        for (int ctl = 0; ctl < 4; ctl++)
          acc[rt][ctl] = __builtin_amdgcn_mfma_f32_16x16x32_bf16(
              afr[rt], bfr[ctl], acc[rt][ctl], 0, 0, 0);
    }

    unsigned short* dstb = (wave < 2) ? Z : S;
    int s0 = 64*(wave & 1) + n*4;
#pragma unroll
    for (int rt = 0; rt < 4; rt++){
#pragma unroll
      for (int r = 0; r < 4; r++){
        int grow = row0 + rt*16 + q*4 + r;
        if (grow < N){
          float v0 = acc[rt][0][r] + bias[0];
          float v1 = acc[rt][1][r] + bias[1];
          float v2 = acc[rt][2][r] + bias[2];
          float v3 = acc[rt][3][r] + bias[3];
          u32x2 u;
          u[0] = ((unsigned)f2bf(v1) << 16) | (unsigned)f2bf(v0);
          u[1] = ((unsigned)f2bf(v3) << 16) | (unsigned)f2bf(v2);
          u32x2* dp = (u32x2*)(dstb + (size_t)grow*FDIM + s0);
          if (wave < 2) *dp = u;                         // Z: cached (gathered next)
          else __builtin_nontemporal_store(u, dp);       // S: stream
        }
      }
    }
  }
}

// ---------------- fused layer-1 aggregate + layer-2 dual GEMM ----------------
// R6-R11 study: (waves x gather-depth) is conserved through the unified
// VGPR/AGPR file — deeper MLP (v[16], VGPR 148) drops occupancy 16.6->9.5%
// and REGRESSES (79us); clamps at arg2>=3 spill. R4 config (8-deep, (256,2),
// VGPR=100, 64us) is the proven optimum — keep structure exactly.
// R12 cache hygiene only: S loads NT (read-once), epilogue Z2/S stores NT
// (write-once; write-allocate was evicting the 25.6MB Z gather table from L2
// — FETCH 82.5MB vs ~55MB ideal).
__global__ __launch_bounds__(256, 2)
void k_agg_gemm(const unsigned short* __restrict__ Z, unsigned short* __restrict__ S,
                const int* __restrict__ row_off, const int* __restrict__ cnt,
                const int* __restrict__ csr_src,
                const unsigned short* __restrict__ Wcat,
                const float* __restrict__ bl, const float* __restrict__ br,
                unsigned short* __restrict__ Z2, int N, int nrb){
  __shared__ unsigned short lds[64*FDIM];
  const int tid  = threadIdx.x;
  const int wave = tid >> 6;
  const int lane = tid & 63;
  const int n = lane & 15, q = lane >> 4;
  const int g16   = lane & 15;   // pos within 16-lane row-group == 16B chunk idx
  const int gbase = lane & 48;   // first lane of this row-group

  float bias[4];
#pragma unroll
  for (int ctl = 0; ctl < 4; ctl++){
    int ct = wave*4 + ctl;
    if (ct >= 8){ int col = (ct - 8)*16 + n; bias[ctl] = bl[col] + br[col]; }
    else bias[ctl] = 0.0f;
  }

  for (int rb = blockIdx.x; rb < nrb; rb += gridDim.x){
    int row0 = rb*64;
    __syncthreads();
    // ---- staging: build h rows (layer-1 aggregate, permuted space) ----
#pragma unroll
    for (int it = 0; it < 4; it++){
      int r  = (tid >> 4) + it*16;
      int gr = row0 + r;
      bf16x8 p;
      if (gr < N){
        int ro  = row_off[gr];
        int deg = cnt[gr];
        float inv = 1.0f / (float)(deg > 1 ? deg : 1);
        float hacc[8];
#pragma unroll
        for (int z = 0; z < 8; z++) hacc[z] = 0.f;
        for (int base = 0; base < deg; base += 16){
          int m = deg - base; if (m > 16) m = 16;
          int sidx = (g16 < m) ? csr_src[ro + base + g16] : 0;
          for (int j = 0; j < m; j += 8){
            int id[8];
#pragma unroll
            for (int t = 0; t < 8; t++){
              int sl = j + t; if (sl >= m) sl = 0;      // group-uniform clamp
              id[t] = __shfl(sidx, gbase + sl);
            }
            uint4 v[8];
#pragma unroll
            for (int t = 0; t < 8; t++){
              unsigned u = (unsigned)id[t];
              if (u > (unsigned)N) u = (unsigned)N;     // defensive (row N = zeros)
              v[t] = *(const uint4*)(Z + (size_t)u*FDIM + g16*8);  // 8 gathers in flight
            }
#pragma unroll
            for (int t = 0; t < 8; t++){
              if (j + t < m){
                hacc[0] += __uint_as_float(v[t].x << 16);
                hacc[1] += __uint_as_float(v[t].x & 0xFFFF0000u);
                hacc[2] += __uint_as_float(v[t].y << 16);
                hacc[3] += __uint_as_float(v[t].y & 0xFFFF0000u);
                hacc[4] += __uint_as_float(v[t].z << 16);
                hacc[5] += __uint_as_float(v[t].z & 0xFFFF0000u);
                hacc[6] += __uint_as_float(v[t].w << 16);
                hacc[7] += __uint_as_float(v[t].w & 0xFFFF0000u);
              }
            }
          }
        }
        u32x4 sv = __builtin_nontemporal_load((const u32x4*)(S + (size_t)gr*FDIM + g16*8));
        float s0 = __uint_as_float(sv[0] << 16), s1 = __uint_as_float(sv[0] & 0xFFFF0000u);
        float s2 = __uint_as_float(sv[1] << 16), s3 = __uint_as_float(sv[1] & 0xFFFF0000u);
        float s4 = __uint_as_float(sv[2] << 16), s5 = __uint_as_float(sv[2] & 0xFFFF0000u);
        float s6 = __uint_as_float(sv[3] << 16), s7 = __uint_as_float(sv[3] & 0xFFFF0000u);
        p[0] = (short)f2bf(fmaxf(hacc[0]*inv + s0, 0.f));
        p[1] = (short)f2bf(fmaxf(hacc[1]*inv + s1, 0.f));
        p[2] = (short)f2bf(fmaxf(hacc[2]*inv + s2, 0.f));
        p[3] = (short)f2bf(fmaxf(hacc[3]*inv + s3, 0.f));
        p[4] = (short)f2bf(fmaxf(hacc[4]*inv + s4, 0.f));
        p[5] = (short)f2bf(fmaxf(hacc[5]*inv + s5, 0.f));
        p[6] = (short)f2bf(fmaxf(hacc[6]*inv + s6, 0.f));
        p[7] = (short)f2bf(fmaxf(hacc[7]*inv + s7, 0.f));
      } else {
#pragma unroll
        for (int z = 0; z < 8; z++) p[z] = 0;
      }
      *(bf16x8*)(lds + r*FDIM + ((g16 ^ (r & 15)) * 8)) = p;
    }
    __syncthreads();

    // ---- MFMA with layer-2 weights ----
    f32x4 acc[4][4];
#pragma unroll
    for (int rt = 0; rt < 4; rt++)
#pragma unroll
      for (int ctl = 0; ctl < 4; ctl++)
        acc[rt][ctl] = (f32x4){0.f, 0.f, 0.f, 0.f};

#pragma unroll
    for (int kk = 0; kk < 4; kk++){
      bf16x8 bfr[4];
#pragma unroll
      for (int ctl = 0; ctl < 4; ctl++){
        int row = (wave*4 + ctl)*16 + n;
        bfr[ctl] = *(const bf16x8*)(Wcat + row*FDIM + kk*32 + q*8);
      }
      bf16x8 afr[4];
#pragma unroll
      for (int rt = 0; rt < 4; rt++){
        int r = rt*16 + n;
        int c16 = (kk*4 + q) ^ n;
        afr[rt] = *(const bf16x8*)(lds + r*FDIM + c16*8);
      }
#pragma unroll
      for (int rt = 0; rt < 4; rt++)
#pragma unroll
        for (int ctl = 0; ctl < 4; ctl++)
          acc[rt][ctl] = __builtin_amdgcn_mfma_f32_16x16x32_bf16(
              afr[rt], bfr[ctl], acc[rt][ctl], 0, 0, 0);
    }

    // ---- epilogue: Z2 / S (in place), both NT (write-once streams) ----
    unsigned short* dstb = (wave < 2) ? Z2 : S;
    int s0c = 64*(wave & 1) + n*4;
#pragma unroll
    for (int rt = 0; rt < 4; rt++){
#pragma unroll
      for (int r = 0; r < 4; r++){
        int grow = row0 + rt*16 + q*4 + r;
        if (grow < N){
          float v0 = acc[rt][0][r] + bias[0];
          float v1 = acc[rt][1][r] + bias[1];
          float v2 = acc[rt][2][r] + bias[2];
          float v3 = acc[rt][3][r] + bias[3];
          u32x2 u;
          u[0] = ((unsigned)f2bf(v1) << 16) | (unsigned)f2bf(v0);
          u[1] = ((unsigned)f2bf(v3) << 16) | (unsigned)f2bf(v2);
          __builtin_nontemporal_store(u, (u32x2*)(dstb + (size_t)grow*FDIM + s0c));
        }
      }
    }
  }
}

// ---------------- final aggregate: out = relu(sum(Z2[src])/deg + S) ----------------
// R9 shape: 64 nodes/block, 16-lane group per node, 16B gathers x8 in flight,
// un-permute through padded LDS, coalesced float4 output.
// R12: S loads NT, Out stores NT (both streams; keeps Z2 gather table in L2).
__global__ __launch_bounds__(256, 2)
void k_aggregate(const unsigned short* __restrict__ Z2, const unsigned short* __restrict__ S,
                 const int* __restrict__ row_off, const int* __restrict__ cnt,
                 const int* __restrict__ csr_src, float* __restrict__ Out, int N, int nrb){
  __shared__ __align__(16) float lds_out[64*132];   // +4 pad per row vs 128
  const int tid   = threadIdx.x;
  const int lane  = tid & 63;
  const int g16   = lane & 15;
  const int gbase = lane & 48;

  for (int rb = blockIdx.x; rb < nrb; rb += gridDim.x){
    int row0 = rb*64;
    __syncthreads();   // protect lds_out against previous iteration's readers
#pragma unroll
    for (int it = 0; it < 4; it++){
      int r  = (tid >> 4) + it*16;
      int gr = row0 + r;
      if (gr < N){
        int ro  = row_off[gr];
        int deg = cnt[gr];
        float inv = 1.0f / (float)(deg > 1 ? deg : 1);
        float hacc[8];
#pragma unroll
        for (int z = 0; z < 8; z++) hacc[z] = 0.f;
        for (int base = 0; base < deg; base += 16){
          int m = deg - base; if (m > 16) m = 16;
          int sidx = (g16 < m) ? csr_src[ro + base + g16] : 0;
          for (int j = 0; j < m; j += 8){
            int id[8];
#pragma unroll
            for (int t = 0; t < 8; t++){
              int sl = j + t; if (sl >= m) sl = 0;      // group-uniform clamp
              id[t] = __shfl(sidx, gbase + sl);
            }
            uint4 v[8];
#pragma unroll
            for (int t = 0; t < 8; t++){
              unsigned u = (unsigned)id[t];
              if (u > (unsigned)N) u = (unsigned)N;     // dummy/defensive -> zero row
              v[t] = *(const uint4*)(Z2 + (size_t)u*FDIM + g16*8);  // 8 gathers in flight
            }
#pragma unroll
            for (int t = 0; t < 8; t++){
              if (j + t < m){
                hacc[0] += __uint_as_float(v[t].x << 16);
                hacc[1] += __uint_as_float(v[t].x & 0xFFFF0000u);
                hacc[2] += __uint_as_float(v[t].y << 16);
                hacc[3] += __uint_as_float(v[t].y & 0xFFFF0000u);
                hacc[4] += __uint_as_float(v[t].z << 16);
                hacc[5] += __uint_as_float(v[t].z & 0xFFFF0000u);
                hacc[6] += __uint_as_float(v[t].w << 16);
                hacc[7] += __uint_as_float(v[t].w & 0xFFFF0000u);
              }
            }
          }
        }
        u32x4 sv = __builtin_nontemporal_load((const u32x4*)(S + (size_t)gr*FDIM + g16*8));
        float s0 = __uint_as_float(sv[0] << 16), s1 = __uint_as_float(sv[0] & 0xFFFF0000u);
        float s2 = __uint_as_float(sv[1] << 16), s3 = __uint_as_float(sv[1] & 0xFFFF0000u);
        float s4 = __uint_as_float(sv[2] << 16), s5 = __uint_as_float(sv[2] & 0xFFFF0000u);
        float s6 = __uint_as_float(sv[3] << 16), s7 = __uint_as_float(sv[3] & 0xFFFF0000u);
        float o[8];
        o[0] = fmaxf(hacc[0]*inv + s0, 0.f);
        o[1] = fmaxf(hacc[1]*inv + s1, 0.f);
        o[2] = fmaxf(hacc[2]*inv + s2, 0.f);
        o[3] = fmaxf(hacc[3]*inv + s3, 0.f);
        o[4] = fmaxf(hacc[4]*inv + s4, 0.f);
        o[5] = fmaxf(hacc[5]*inv + s5, 0.f);
        o[6] = fmaxf(hacc[6]*inv + s6, 0.f);
        o[7] = fmaxf(hacc[7]*inv + s7, 0.f);
        // un-permute into LDS: stored s -> orig c
#pragma unroll
        for (int z = 0; z < 8; z++){
          int s_ = g16*8 + z;
          int hi = s_ >> 6, s6i = s_ & 63;
          int c = ((s6i & 3) + 4*hi)*16 + (s6i >> 2);
          lds_out[r*132 + c] = o[z];
        }
      }
    }
    __syncthreads();
    // coalesced float4 NT write-out
#pragma unroll
    for (int it2 = 0; it2 < 8; it2++){
      int r2  = (tid >> 5) + it2*8;
      int c4  = tid & 31;
      int gr2 = row0 + r2;
      if (gr2 < N){
        f32x4 ov = *(const f32x4*)(lds_out + r2*132 + c4*4);
        __builtin_nontemporal_store(ov, (f32x4*)(Out + (size_t)gr2*FDIM + c4*4));
      }
    }
  }
}

extern "C" void kernel_launch(void* const* d_in, const int* in_sizes, int n_in,
                              void* d_out, int out_size, void* d_ws, size_t ws_size,
                              hipStream_t stream){
  const float* x   = (const float*)d_in[0];
  const int*   eix = (const int*)d_in[1];
  const float* Wl0 = (const float*)d_in[2];
  const float* bl0 = (const float*)d_in[3];
  const float* Wr0 = (const float*)d_in[4];
  const float* br0 = (const float*)d_in[5];
  const float* Wl1 = (const float*)d_in[6];
  const float* bl1 = (const float*)d_in[7];
  const float* Wr1 = (const float*)d_in[8];
  const float* br1 = (const float*)d_in[9];
  float* out = (float*)d_out;

  int N = in_sizes[0] / FDIM;
  int E = in_sizes[1] / 2;
  const int* src = eix;
  const int* dst = eix + E;

  // workspace (Z and Z2 have N+1 rows: row N is the zero dummy row)
  unsigned short* Z    = (unsigned short*)d_ws;
  unsigned short* Z2   = Z  + (size_t)(N + 1)*FDIM;
  unsigned short* S    = Z2 + (size_t)(N + 1)*FDIM;
  unsigned short* Wcat = S  + (size_t)N*FDIM;
  int* cnt     = (int*)(Wcat + 2*256*128);
  int* row_off = cnt + N;
  int* cursor  = row_off + N;
  int* csr_src = cursor + N;                 // capacity: E + 7N (padding bound)
  int* partials= csr_src + (E + 7*N);

  int nb = (N + 255)/256;

  k_init         <<<nb + 256, 256, 0, stream>>>(Wl0, Wr0, Wl1, Wr1, Wcat, cnt,
                                                Z + (size_t)N*FDIM, Z2 + (size_t)N*FDIM, N, nb);
  k_degree       <<<(E + 255)/256, 256, 0, stream>>>(dst, cnt, E);
  k_scan_blocks  <<<nb, 256, 0, stream>>>(cnt, row_off, partials, N);
  k_scan_partials<<<1, 512, 0, stream>>>(partials, nb);
  k_finalize_pad <<<nb, 256, 0, stream>>>(row_off, partials, cursor, cnt, csr_src, N);
  k_fill         <<<(E + 255)/256, 256, 0, stream>>>(src, dst, cursor, csr_src, E);

  int nrb = (N + 63)/64;
  k_dualgemm1<<<512, 256, 0, stream>>>(x, Wcat, bl0, br0, Z, S, N, nrb);
  k_agg_gemm <<<512, 256, 0, stream>>>(Z, S, row_off, cnt, csr_src,
                                       Wcat + 256*128, bl1, br1, Z2, N, nrb);
  k_aggregate<<<1024, 256, 0, stream>>>(Z2, S, row_off, cnt, csr_src, out, N, nrb);
}

// Round 8
// 286.709 us; speedup vs baseline: 1.0510x; 1.0198x over previous
//
#include <hip/hip_runtime.h>

#define FDIM 128

typedef __attribute__((ext_vector_type(8))) short bf16x8;
typedef __attribute__((ext_vector_type(4))) float f32x4;
typedef __attribute__((ext_vector_type(4))) unsigned int u32x4;
typedef __attribute__((ext_vector_type(2))) unsigned int u32x2;

// Column permutation for internal Z/S storage (within a 128-col half):
//   orig c: ct=c>>4, n=c&15  ->  stored s = 64*(ct>=4) + n*4 + (ct&3)
//   inv:    hi=s>>6, s6=s&63, n=s6>>2, ctl=s6&3 -> c = (ctl+4*hi)*16 + n

__device__ __forceinline__ unsigned short f2bf(float f){
  unsigned int u = __float_as_uint(f);
  unsigned int r = u + 0x7FFFu + ((u >> 16) & 1u);
  return (unsigned short)(r >> 16);
}

// ---------------- init: zero cnt, zero dummy Z/Z2 rows, build Wcat ----------------
__global__ void k_init(const float* __restrict__ Wl0, const float* __restrict__ Wr0,
                       const float* __restrict__ Wl1, const float* __restrict__ Wr1,
                       unsigned short* __restrict__ Wcat, int* __restrict__ cnt,
                       unsigned short* __restrict__ Zdummy, unsigned short* __restrict__ Z2dummy,
                       int N, int nb){
  int b = blockIdx.x;
  if (b < nb){
    int i = b*256 + threadIdx.x;
    if (i < N) cnt[i] = 0;
    if (b == 0 && threadIdx.x < FDIM){
      Zdummy[threadIdx.x]  = 0;
      Z2dummy[threadIdx.x] = 0;
    }
  } else {
    int i = (b - nb)*256 + threadIdx.x;     // 0 .. 65535
    int l   = i >> 15;
    int rem = i & 32767;
    int row = rem >> 7, k = rem & 127;
    int ksrc = k;
    if (l == 1){
      int hi = k >> 6, s6 = k & 63;
      ksrc = ((s6 & 3) + 4*hi)*16 + (s6 >> 2);   // invPerm(k)
    }
    const float* W = (l == 0) ? ((row < 128) ? Wl0 : Wr0)
                              : ((row < 128) ? Wl1 : Wr1);
    Wcat[i] = f2bf(W[(row & 127)*128 + ksrc]);
  }
}

// ---------------- degree ----------------
__global__ void k_degree(const int* __restrict__ dst, int* __restrict__ cnt, int E){
  int e = blockIdx.x*256 + threadIdx.x;
  if (e < E) atomicAdd(&cnt[dst[e]], 1);
}

// ---------------- hierarchical scan over PADDED degrees (R5-proven) ----------------
__global__ void k_scan_blocks(const int* __restrict__ cnt, int* __restrict__ excl,
                              int* __restrict__ partials, int N){
  __shared__ int s[256];
  int tid = threadIdx.x;
  int i = blockIdx.x*256 + tid;
  int v = (i < N) ? ((cnt[i] + 7) & ~7) : 0;
  s[tid] = v; __syncthreads();
  for (int off = 1; off < 256; off <<= 1){
    int t = (tid >= off) ? s[tid - off] : 0;
    __syncthreads();
    s[tid] += t;
    __syncthreads();
  }
  if (i < N) excl[i] = s[tid] - v;
  if (tid == 255) partials[blockIdx.x] = s[255];
}

__global__ void k_scan_partials(int* __restrict__ partials, int nb){
  __shared__ int s[512];
  int tid = threadIdx.x;
  int v = (tid < nb) ? partials[tid] : 0;
  s[tid] = v; __syncthreads();
  for (int off = 1; off < 512; off <<= 1){
    int t = (tid >= off) ? s[tid - off] : 0;
    __syncthreads();
    s[tid] += t;
    __syncthreads();
  }
  if (tid < nb) partials[tid] = s[tid] - v;
}

// finalize + pad fused (pad writes slots >= deg, fill writes < deg: disjoint,
// so padding can happen before k_fill)
__global__ void k_finalize_pad(int* __restrict__ row_off, const int* __restrict__ partials,
                               int* __restrict__ cursor, const int* __restrict__ cnt,
                               int* __restrict__ csr_src, int N){
  int i = blockIdx.x*256 + threadIdx.x;
  if (i >= N) return;
  int ro = row_off[i] + partials[blockIdx.x];
  row_off[i] = ro;
  cursor[i]  = ro;
  int d  = cnt[i];
  int pd = (d + 7) & ~7;
  for (int p = d; p < pd; p++) csr_src[ro + p] = N;
}

// ---------------- fill ----------------
__global__ void k_fill(const int* __restrict__ src, const int* __restrict__ dst,
                       int* __restrict__ cursor, int* __restrict__ csr_src, int E){
  int e = blockIdx.x*256 + threadIdx.x;
  if (e >= E) return;
  int d = dst[e];
  int pos = atomicAdd(&cursor[d], 1);
  csr_src[pos] = src[e];
}

// ---------------- layer-1 dual GEMM: Z = X@Wl^T, S = X@Wr^T + (bl+br) ----------------
// fp32 A input, permuted-col bf16 output. Register-prefetch pipelined (R5).
// R0-proven config: grid 512, (256,2).
// R13: X loads CACHED again (re-read every iteration; L3-resident — R7's NT
// loads forfeited that). S stores NT (read-once stream); Z stores cached
// (agg_gemm's gather table).
__global__ __launch_bounds__(256, 2)
void k_dualgemm1(const float* __restrict__ X, const unsigned short* __restrict__ Wcat,
                 const float* __restrict__ bl, const float* __restrict__ br,
                 unsigned short* __restrict__ Z, unsigned short* __restrict__ S,
                 int N, int nrb){
  __shared__ unsigned short lds[64*FDIM];
  const int tid  = threadIdx.x;
  const int wave = tid >> 6;
  const int lane = tid & 63;
  const int n = lane & 15, q = lane >> 4;

  float bias[4];
#pragma unroll
  for (int ctl = 0; ctl < 4; ctl++){
    int ct = wave*4 + ctl;
    if (ct >= 8){ int col = (ct - 8)*16 + n; bias[ctl] = bl[col] + br[col]; }
    else bias[ctl] = 0.0f;
  }

  f32x4 pf[8];
  const int r_   = tid >> 4;
  const int c16_ = tid & 15;

  auto issue_load = [&](int rb){
    int row0 = rb*64;
#pragma unroll
    for (int it = 0; it < 4; it++){
      int r  = r_ + it*16;
      int gr = row0 + r;
      if (gr < N){
        const f32x4* sp = (const f32x4*)(X + (size_t)gr*FDIM + c16_*8);
        pf[2*it]   = sp[0];
        pf[2*it+1] = sp[1];
      } else {
        pf[2*it]   = (f32x4){0.f,0.f,0.f,0.f};
        pf[2*it+1] = (f32x4){0.f,0.f,0.f,0.f};
      }
    }
  };

  int rb = blockIdx.x;
  if (rb < nrb) issue_load(rb);

  for (; rb < nrb; rb += gridDim.x){
    int row0 = rb*64;
    __syncthreads();
#pragma unroll
    for (int it = 0; it < 4; it++){
      int r = r_ + it*16;
      f32x4 v0 = pf[2*it], v1 = pf[2*it+1];
      bf16x8 p;
      p[0] = (short)f2bf(v0[0]); p[1] = (short)f2bf(v0[1]);
      p[2] = (short)f2bf(v0[2]); p[3] = (short)f2bf(v0[3]);
      p[4] = (short)f2bf(v1[0]); p[5] = (short)f2bf(v1[1]);
      p[6] = (short)f2bf(v1[2]); p[7] = (short)f2bf(v1[3]);
      *(bf16x8*)(lds + r*FDIM + ((c16_ ^ (r & 15)) * 8)) = p;
    }
    __syncthreads();

    int rbn = rb + gridDim.x;
    if (rbn < nrb) issue_load(rbn);

    f32x4 acc[4][4];
#pragma unroll
    for (int rt = 0; rt < 4; rt++)
#pragma unroll
      for (int ctl = 0; ctl < 4; ctl++)
        acc[rt][ctl] = (f32x4){0.f, 0.f, 0.f, 0.f};

#pragma unroll
    for (int kk = 0; kk < 4; kk++){
      bf16x8 bfr[4];
#pragma unroll
      for (int ctl = 0; ctl < 4; ctl++){
        int row = (wave*4 + ctl)*16 + n;
        bfr[ctl] = *(const bf16x8*)(Wcat + row*FDIM + kk*32 + q*8);
      }
      bf16x8 afr[4];
#pragma unroll
      for (int rt = 0; rt < 4; rt++){
        int r = rt*16 + n;
        int c16 = (kk*4 + q) ^ n;
        afr[rt] = *(const bf16x8*)(lds + r*FDIM + c16*8);
      }
#pragma unroll
      for (int rt = 0; rt < 4; rt++)
#pragma unroll
        for (int ctl = 0; ctl < 4; ctl++)
          acc[rt][ctl] = __builtin_amdgcn_mfma_f32_16x16x32_bf16(
              afr[rt], bfr[ctl], acc[rt][ctl], 0, 0, 0);
    }

    unsigned short* dstb = (wave < 2) ? Z : S;
    int s0 = 64*(wave & 1) + n*4;
#pragma unroll
    for (int rt = 0; rt < 4; rt++){
#pragma unroll
      for (int r = 0; r < 4; r++){
        int grow = row0 + rt*16 + q*4 + r;
        if (grow < N){
          float v0 = acc[rt][0][r] + bias[0];
          float v1 = acc[rt][1][r] + bias[1];
          float v2 = acc[rt][2][r] + bias[2];
          float v3 = acc[rt][3][r] + bias[3];
          u32x2 u;
          u[0] = ((unsigned)f2bf(v1) << 16) | (unsigned)f2bf(v0);
          u[1] = ((unsigned)f2bf(v3) << 16) | (unsigned)f2bf(v2);
          u32x2* dp = (u32x2*)(dstb + (size_t)grow*FDIM + s0);
          if (wave < 2) *dp = u;                         // Z: cached (gathered next)
          else __builtin_nontemporal_store(u, dp);       // S: stream
        }
      }
    }
  }
}

// ---------------- fused layer-1 aggregate + layer-2 dual GEMM ----------------
// R6-R11 study: (waves x gather-depth) is conserved through the unified
// VGPR/AGPR file — R4 structure (8-deep, (256,2), VGPR~100) is the optimum.
// R12 win kept: S loads NT, S epilogue stores NT (FETCH 82.5->80MB, 63->60.5us).
// R13 fix: Z2 epilogue stores CACHED — Z2 is k_aggregate's gather table;
// R12's NT store evicted it and slowed the downstream kernel (+11us total).
__global__ __launch_bounds__(256, 2)
void k_agg_gemm(const unsigned short* __restrict__ Z, unsigned short* __restrict__ S,
                const int* __restrict__ row_off, const int* __restrict__ cnt,
                const int* __restrict__ csr_src,
                const unsigned short* __restrict__ Wcat,
                const float* __restrict__ bl, const float* __restrict__ br,
                unsigned short* __restrict__ Z2, int N, int nrb){
  __shared__ unsigned short lds[64*FDIM];
  const int tid  = threadIdx.x;
  const int wave = tid >> 6;
  const int lane = tid & 63;
  const int n = lane & 15, q = lane >> 4;
  const int g16   = lane & 15;   // pos within 16-lane row-group == 16B chunk idx
  const int gbase = lane & 48;   // first lane of this row-group

  float bias[4];
#pragma unroll
  for (int ctl = 0; ctl < 4; ctl++){
    int ct = wave*4 + ctl;
    if (ct >= 8){ int col = (ct - 8)*16 + n; bias[ctl] = bl[col] + br[col]; }
    else bias[ctl] = 0.0f;
  }

  for (int rb = blockIdx.x; rb < nrb; rb += gridDim.x){
    int row0 = rb*64;
    __syncthreads();
    // ---- staging: build h rows (layer-1 aggregate, permuted space) ----
#pragma unroll
    for (int it = 0; it < 4; it++){
      int r  = (tid >> 4) + it*16;
      int gr = row0 + r;
      bf16x8 p;
      if (gr < N){
        int ro  = row_off[gr];
        int deg = cnt[gr];
        float inv = 1.0f / (float)(deg > 1 ? deg : 1);
        float hacc[8];
#pragma unroll
        for (int z = 0; z < 8; z++) hacc[z] = 0.f;
        for (int base = 0; base < deg; base += 16){
          int m = deg - base; if (m > 16) m = 16;
          int sidx = (g16 < m) ? csr_src[ro + base + g16] : 0;
          for (int j = 0; j < m; j += 8){
            int id[8];
#pragma unroll
            for (int t = 0; t < 8; t++){
              int sl = j + t; if (sl >= m) sl = 0;      // group-uniform clamp
              id[t] = __shfl(sidx, gbase + sl);
            }
            uint4 v[8];
#pragma unroll
            for (int t = 0; t < 8; t++){
              unsigned u = (unsigned)id[t];
              if (u > (unsigned)N) u = (unsigned)N;     // defensive (row N = zeros)
              v[t] = *(const uint4*)(Z + (size_t)u*FDIM + g16*8);  // 8 gathers in flight
            }
#pragma unroll
            for (int t = 0; t < 8; t++){
              if (j + t < m){
                hacc[0] += __uint_as_float(v[t].x << 16);
                hacc[1] += __uint_as_float(v[t].x & 0xFFFF0000u);
                hacc[2] += __uint_as_float(v[t].y << 16);
                hacc[3] += __uint_as_float(v[t].y & 0xFFFF0000u);
                hacc[4] += __uint_as_float(v[t].z << 16);
                hacc[5] += __uint_as_float(v[t].z & 0xFFFF0000u);
                hacc[6] += __uint_as_float(v[t].w << 16);
                hacc[7] += __uint_as_float(v[t].w & 0xFFFF0000u);
              }
            }
          }
        }
        u32x4 sv = __builtin_nontemporal_load((const u32x4*)(S + (size_t)gr*FDIM + g16*8));
        float s0 = __uint_as_float(sv[0] << 16), s1 = __uint_as_float(sv[0] & 0xFFFF0000u);
        float s2 = __uint_as_float(sv[1] << 16), s3 = __uint_as_float(sv[1] & 0xFFFF0000u);
        float s4 = __uint_as_float(sv[2] << 16), s5 = __uint_as_float(sv[2] & 0xFFFF0000u);
        float s6 = __uint_as_float(sv[3] << 16), s7 = __uint_as_float(sv[3] & 0xFFFF0000u);
        p[0] = (short)f2bf(fmaxf(hacc[0]*inv + s0, 0.f));
        p[1] = (short)f2bf(fmaxf(hacc[1]*inv + s1, 0.f));
        p[2] = (short)f2bf(fmaxf(hacc[2]*inv + s2, 0.f));
        p[3] = (short)f2bf(fmaxf(hacc[3]*inv + s3, 0.f));
        p[4] = (short)f2bf(fmaxf(hacc[4]*inv + s4, 0.f));
        p[5] = (short)f2bf(fmaxf(hacc[5]*inv + s5, 0.f));
        p[6] = (short)f2bf(fmaxf(hacc[6]*inv + s6, 0.f));
        p[7] = (short)f2bf(fmaxf(hacc[7]*inv + s7, 0.f));
      } else {
#pragma unroll
        for (int z = 0; z < 8; z++) p[z] = 0;
      }
      *(bf16x8*)(lds + r*FDIM + ((g16 ^ (r & 15)) * 8)) = p;
    }
    __syncthreads();

    // ---- MFMA with layer-2 weights ----
    f32x4 acc[4][4];
#pragma unroll
    for (int rt = 0; rt < 4; rt++)
#pragma unroll
      for (int ctl = 0; ctl < 4; ctl++)
        acc[rt][ctl] = (f32x4){0.f, 0.f, 0.f, 0.f};

#pragma unroll
    for (int kk = 0; kk < 4; kk++){
      bf16x8 bfr[4];
#pragma unroll
      for (int ctl = 0; ctl < 4; ctl++){
        int row = (wave*4 + ctl)*16 + n;
        bfr[ctl] = *(const bf16x8*)(Wcat + row*FDIM + kk*32 + q*8);
      }
      bf16x8 afr[4];
#pragma unroll
      for (int rt = 0; rt < 4; rt++){
        int r = rt*16 + n;
        int c16 = (kk*4 + q) ^ n;
        afr[rt] = *(const bf16x8*)(lds + r*FDIM + c16*8);
      }
#pragma unroll
      for (int rt = 0; rt < 4; rt++)
#pragma unroll
        for (int ctl = 0; ctl < 4; ctl++)
          acc[rt][ctl] = __builtin_amdgcn_mfma_f32_16x16x32_bf16(
              afr[rt], bfr[ctl], acc[rt][ctl], 0, 0, 0);
    }

    // ---- epilogue: Z2 cached (next kernel's gather table), S NT (stream) ----
    unsigned short* dstb = (wave < 2) ? Z2 : S;
    int s0c = 64*(wave & 1) + n*4;
#pragma unroll
    for (int rt = 0; rt < 4; rt++){
#pragma unroll
      for (int r = 0; r < 4; r++){
        int grow = row0 + rt*16 + q*4 + r;
        if (grow < N){
          float v0 = acc[rt][0][r] + bias[0];
          float v1 = acc[rt][1][r] + bias[1];
          float v2 = acc[rt][2][r] + bias[2];
          float v3 = acc[rt][3][r] + bias[3];
          u32x2 u;
          u[0] = ((unsigned)f2bf(v1) << 16) | (unsigned)f2bf(v0);
          u[1] = ((unsigned)f2bf(v3) << 16) | (unsigned)f2bf(v2);
          u32x2* dp = (u32x2*)(dstb + (size_t)grow*FDIM + s0c);
          if (wave < 2) *dp = u;                         // Z2: cached
          else __builtin_nontemporal_store(u, dp);       // S: stream
        }
      }
    }
  }
}

// ---------------- final aggregate: out = relu(sum(Z2[src])/deg + S) ----------------
// R9 shape: 64 nodes/block, 16-lane group per node, 16B gathers x8 in flight,
// un-permute through padded LDS, coalesced float4 output.
// R12: S loads NT, Out stores NT (both streams; keeps Z2 gather table in L2).
__global__ __launch_bounds__(256, 2)
void k_aggregate(const unsigned short* __restrict__ Z2, const unsigned short* __restrict__ S,
                 const int* __restrict__ row_off, const int* __restrict__ cnt,
                 const int* __restrict__ csr_src, float* __restrict__ Out, int N, int nrb){
  __shared__ __align__(16) float lds_out[64*132];   // +4 pad per row vs 128
  const int tid   = threadIdx.x;
  const int lane  = tid & 63;
  const int g16   = lane & 15;
  const int gbase = lane & 48;

  for (int rb = blockIdx.x; rb < nrb; rb += gridDim.x){
    int row0 = rb*64;
    __syncthreads();   // protect lds_out against previous iteration's readers
#pragma unroll
    for (int it = 0; it < 4; it++){
      int r  = (tid >> 4) + it*16;
      int gr = row0 + r;
      if (gr < N){
        int ro  = row_off[gr];
        int deg = cnt[gr];
        float inv = 1.0f / (float)(deg > 1 ? deg : 1);
        float hacc[8];
#pragma unroll
        for (int z = 0; z < 8; z++) hacc[z] = 0.f;
        for (int base = 0; base < deg; base += 16){
          int m = deg - base; if (m > 16) m = 16;
          int sidx = (g16 < m) ? csr_src[ro + base + g16] : 0;
          for (int j = 0; j < m; j += 8){
            int id[8];
#pragma unroll
            for (int t = 0; t < 8; t++){
              int sl = j + t; if (sl >= m) sl = 0;      // group-uniform clamp
              id[t] = __shfl(sidx, gbase + sl);
            }
            uint4 v[8];
#pragma unroll
            for (int t = 0; t < 8; t++){
              unsigned u = (unsigned)id[t];
              if (u > (unsigned)N) u = (unsigned)N;     // dummy/defensive -> zero row
              v[t] = *(const uint4*)(Z2 + (size_t)u*FDIM + g16*8);  // 8 gathers in flight
            }
#pragma unroll
            for (int t = 0; t < 8; t++){
              if (j + t < m){
                hacc[0] += __uint_as_float(v[t].x << 16);
                hacc[1] += __uint_as_float(v[t].x & 0xFFFF0000u);
                hacc[2] += __uint_as_float(v[t].y << 16);
                hacc[3] += __uint_as_float(v[t].y & 0xFFFF0000u);
                hacc[4] += __uint_as_float(v[t].z << 16);
                hacc[5] += __uint_as_float(v[t].z & 0xFFFF0000u);
                hacc[6] += __uint_as_float(v[t].w << 16);
                hacc[7] += __uint_as_float(v[t].w & 0xFFFF0000u);
              }
            }
          }
        }
        u32x4 sv = __builtin_nontemporal_load((const u32x4*)(S + (size_t)gr*FDIM + g16*8));
        float s0 = __uint_as_float(sv[0] << 16), s1 = __uint_as_float(sv[0] & 0xFFFF0000u);
        float s2 = __uint_as_float(sv[1] << 16), s3 = __uint_as_float(sv[1] & 0xFFFF0000u);
        float s4 = __uint_as_float(sv[2] << 16), s5 = __uint_as_float(sv[2] & 0xFFFF0000u);
        float s6 = __uint_as_float(sv[3] << 16), s7 = __uint_as_float(sv[3] & 0xFFFF0000u);
        float o[8];
        o[0] = fmaxf(hacc[0]*inv + s0, 0.f);
        o[1] = fmaxf(hacc[1]*inv + s1, 0.f);
        o[2] = fmaxf(hacc[2]*inv + s2, 0.f);
        o[3] = fmaxf(hacc[3]*inv + s3, 0.f);
        o[4] = fmaxf(hacc[4]*inv + s4, 0.f);
        o[5] = fmaxf(hacc[5]*inv + s5, 0.f);
        o[6] = fmaxf(hacc[6]*inv + s6, 0.f);
        o[7] = fmaxf(hacc[7]*inv + s7, 0.f);
        // un-permute into LDS: stored s -> orig c
#pragma unroll
        for (int z = 0; z < 8; z++){
          int s_ = g16*8 + z;
          int hi = s_ >> 6, s6i = s_ & 63;
          int c = ((s6i & 3) + 4*hi)*16 + (s6i >> 2);
          lds_out[r*132 + c] = o[z];
        }
      }
    }
    __syncthreads();
    // coalesced float4 NT write-out
#pragma unroll
    for (int it2 = 0; it2 < 8; it2++){
      int r2  = (tid >> 5) + it2*8;
      int c4  = tid & 31;
      int gr2 = row0 + r2;
      if (gr2 < N){
        f32x4 ov = *(const f32x4*)(lds_out + r2*132 + c4*4);
        __builtin_nontemporal_store(ov, (f32x4*)(Out + (size_t)gr2*FDIM + c4*4));
      }
    }
  }
}

extern "C" void kernel_launch(void* const* d_in, const int* in_sizes, int n_in,
                              void* d_out, int out_size, void* d_ws, size_t ws_size,
                              hipStream_t stream){
  const float* x   = (const float*)d_in[0];
  const int*   eix = (const int*)d_in[1];
  const float* Wl0 = (const float*)d_in[2];
  const float* bl0 = (const float*)d_in[3];
  const float* Wr0 = (const float*)d_in[4];
  const float* br0 = (const float*)d_in[5];
  const float* Wl1 = (const float*)d_in[6];
  const float* bl1 = (const float*)d_in[7];
  const float* Wr1 = (const float*)d_in[8];
  const float* br1 = (const float*)d_in[9];
  float* out = (float*)d_out;

  int N = in_sizes[0] / FDIM;
  int E = in_sizes[1] / 2;
  const int* src = eix;
  const int* dst = eix + E;

  // workspace (Z and Z2 have N+1 rows: row N is the zero dummy row)
  unsigned short* Z    = (unsigned short*)d_ws;
  unsigned short* Z2   = Z  + (size_t)(N + 1)*FDIM;
  unsigned short* S    = Z2 + (size_t)(N + 1)*FDIM;
  unsigned short* Wcat = S  + (size_t)N*FDIM;
  int* cnt     = (int*)(Wcat + 2*256*128);
  int* row_off = cnt + N;
  int* cursor  = row_off + N;
  int* csr_src = cursor + N;                 // capacity: E + 7N (padding bound)
  int* partials= csr_src + (E + 7*N);

  int nb = (N + 255)/256;

  k_init         <<<nb + 256, 256, 0, stream>>>(Wl0, Wr0, Wl1, Wr1, Wcat, cnt,
                                                Z + (size_t)N*FDIM, Z2 + (size_t)N*FDIM, N, nb);
  k_degree       <<<(E + 255)/256, 256, 0, stream>>>(dst, cnt, E);
  k_scan_blocks  <<<nb, 256, 0, stream>>>(cnt, row_off, partials, N);
  k_scan_partials<<<1, 512, 0, stream>>>(partials, nb);
  k_finalize_pad <<<nb, 256, 0, stream>>>(row_off, partials, cursor, cnt, csr_src, N);
  k_fill         <<<(E + 255)/256, 256, 0, stream>>>(src, dst, cursor, csr_src, E);

  int nrb = (N + 63)/64;
  k_dualgemm1<<<512, 256, 0, stream>>>(x, Wcat, bl0, br0, Z, S, N, nrb);
  k_agg_gemm <<<512, 256, 0, stream>>>(Z, S, row_off, cnt, csr_src,
                                       Wcat + 256*128, bl1, br1, Z2, N, nrb);
  k_aggregate<<<1024, 256, 0, stream>>>(Z2, S, row_off, cnt, csr_src, out, N, nrb);
}

// Round 9
// 268.743 us; speedup vs baseline: 1.1212x; 1.0669x over previous
//
#include <hip/hip_runtime.h>

#define FDIM 128

typedef __attribute__((ext_vector_type(8))) short bf16x8;
typedef __attribute__((ext_vector_type(4))) float f32x4;
typedef __attribute__((ext_vector_type(4))) unsigned int u32x4;
typedef __attribute__((ext_vector_type(2))) unsigned int u32x2;

// Column permutation for internal Z/S storage (within a 128-col half):
//   orig c: ct=c>>4, n=c&15  ->  stored s = 64*(ct>=4) + n*4 + (ct&3)
//   inv:    hi=s>>6, s6=s&63, n=s6>>2, ctl=s6&3 -> c = (ctl+4*hi)*16 + n

__device__ __forceinline__ unsigned short f2bf(float f){
  unsigned int u = __float_as_uint(f);
  unsigned int r = u + 0x7FFFu + ((u >> 16) & 1u);
  return (unsigned short)(r >> 16);
}

// ---------------- init: zero cnt, zero dummy Z/Z2 rows, build Wcat ----------------
__global__ void k_init(const float* __restrict__ Wl0, const float* __restrict__ Wr0,
                       const float* __restrict__ Wl1, const float* __restrict__ Wr1,
                       unsigned short* __restrict__ Wcat, int* __restrict__ cnt,
                       unsigned short* __restrict__ Zdummy, unsigned short* __restrict__ Z2dummy,
                       int N, int nb){
  int b = blockIdx.x;
  if (b < nb){
    int i = b*256 + threadIdx.x;
    if (i < N) cnt[i] = 0;
    if (b == 0 && threadIdx.x < FDIM){
      Zdummy[threadIdx.x]  = 0;
      Z2dummy[threadIdx.x] = 0;
    }
  } else {
    int i = (b - nb)*256 + threadIdx.x;     // 0 .. 65535
    int l   = i >> 15;
    int rem = i & 32767;
    int row = rem >> 7, k = rem & 127;
    int ksrc = k;
    if (l == 1){
      int hi = k >> 6, s6 = k & 63;
      ksrc = ((s6 & 3) + 4*hi)*16 + (s6 >> 2);   // invPerm(k)
    }
    const float* W = (l == 0) ? ((row < 128) ? Wl0 : Wr0)
                              : ((row < 128) ? Wl1 : Wr1);
    Wcat[i] = f2bf(W[(row & 127)*128 + ksrc]);
  }
}

// ---------------- degree ----------------
__global__ void k_degree(const int* __restrict__ dst, int* __restrict__ cnt, int E){
  int e = blockIdx.x*256 + threadIdx.x;
  if (e < E) atomicAdd(&cnt[dst[e]], 1);
}

// ---------------- hierarchical scan over PADDED degrees ----------------
__global__ void k_scan_blocks(const int* __restrict__ cnt, int* __restrict__ excl,
                              int* __restrict__ partials, int N){
  __shared__ int s[256];
  int tid = threadIdx.x;
  int i = blockIdx.x*256 + tid;
  int v = (i < N) ? ((cnt[i] + 7) & ~7) : 0;
  s[tid] = v; __syncthreads();
  for (int off = 1; off < 256; off <<= 1){
    int t = (tid >= off) ? s[tid - off] : 0;
    __syncthreads();
    s[tid] += t;
    __syncthreads();
  }
  if (i < N) excl[i] = s[tid] - v;
  if (tid == 255) partials[blockIdx.x] = s[255];
}

__global__ void k_scan_partials(int* __restrict__ partials, int nb){
  __shared__ int s[512];
  int tid = threadIdx.x;
  int v = (tid < nb) ? partials[tid] : 0;
  s[tid] = v; __syncthreads();
  for (int off = 1; off < 512; off <<= 1){
    int t = (tid >= off) ? s[tid - off] : 0;
    __syncthreads();
    s[tid] += t;
    __syncthreads();
  }
  if (tid < nb) partials[tid] = s[tid] - v;
}

// finalize + pad fused (pad writes slots >= deg, fill writes < deg: disjoint)
__global__ void k_finalize_pad(int* __restrict__ row_off, const int* __restrict__ partials,
                               int* __restrict__ cursor, const int* __restrict__ cnt,
                               int* __restrict__ csr_src, int N){
  int i = blockIdx.x*256 + threadIdx.x;
  if (i >= N) return;
  int ro = row_off[i] + partials[blockIdx.x];
  row_off[i] = ro;
  cursor[i]  = ro;
  int d  = cnt[i];
  int pd = (d + 7) & ~7;
  for (int p = d; p < pd; p++) csr_src[ro + p] = N;
}

// ---------------- fill ----------------
__global__ void k_fill(const int* __restrict__ src, const int* __restrict__ dst,
                       int* __restrict__ cursor, int* __restrict__ csr_src, int E){
  int e = blockIdx.x*256 + threadIdx.x;
  if (e >= E) return;
  int d = dst[e];
  int pos = atomicAdd(&cursor[d], 1);
  csr_src[pos] = src[e];
}

// ---------------- layer-1 dual GEMM: Z = X@Wl^T, S = X@Wr^T + (bl+br) ----------------
// R13 config: grid 512, (256,2); X cached, S stores NT, Z stores cached.
__global__ __launch_bounds__(256, 2)
void k_dualgemm1(const float* __restrict__ X, const unsigned short* __restrict__ Wcat,
                 const float* __restrict__ bl, const float* __restrict__ br,
                 unsigned short* __restrict__ Z, unsigned short* __restrict__ S,
                 int N, int nrb){
  __shared__ unsigned short lds[64*FDIM];
  const int tid  = threadIdx.x;
  const int wave = tid >> 6;
  const int lane = tid & 63;
  const int n = lane & 15, q = lane >> 4;

  float bias[4];
#pragma unroll
  for (int ctl = 0; ctl < 4; ctl++){
    int ct = wave*4 + ctl;
    if (ct >= 8){ int col = (ct - 8)*16 + n; bias[ctl] = bl[col] + br[col]; }
    else bias[ctl] = 0.0f;
  }

  f32x4 pf[8];
  const int r_   = tid >> 4;
  const int c16_ = tid & 15;

  auto issue_load = [&](int rb){
    int row0 = rb*64;
#pragma unroll
    for (int it = 0; it < 4; it++){
      int r  = r_ + it*16;
      int gr = row0 + r;
      if (gr < N){
        const f32x4* sp = (const f32x4*)(X + (size_t)gr*FDIM + c16_*8);
        pf[2*it]   = sp[0];
        pf[2*it+1] = sp[1];
      } else {
        pf[2*it]   = (f32x4){0.f,0.f,0.f,0.f};
        pf[2*it+1] = (f32x4){0.f,0.f,0.f,0.f};
      }
    }
  };

  int rb = blockIdx.x;
  if (rb < nrb) issue_load(rb);

  for (; rb < nrb; rb += gridDim.x){
    int row0 = rb*64;
    __syncthreads();
#pragma unroll
    for (int it = 0; it < 4; it++){
      int r = r_ + it*16;
      f32x4 v0 = pf[2*it], v1 = pf[2*it+1];
      bf16x8 p;
      p[0] = (short)f2bf(v0[0]); p[1] = (short)f2bf(v0[1]);
      p[2] = (short)f2bf(v0[2]); p[3] = (short)f2bf(v0[3]);
      p[4] = (short)f2bf(v1[0]); p[5] = (short)f2bf(v1[1]);
      p[6] = (short)f2bf(v1[2]); p[7] = (short)f2bf(v1[3]);
      *(bf16x8*)(lds + r*FDIM + ((c16_ ^ (r & 15)) * 8)) = p;
    }
    __syncthreads();

    int rbn = rb + gridDim.x;
    if (rbn < nrb) issue_load(rbn);

    f32x4 acc[4][4];
#pragma unroll
    for (int rt = 0; rt < 4; rt++)
#pragma unroll
      for (int ctl = 0; ctl < 4; ctl++)
        acc[rt][ctl] = (f32x4){0.f, 0.f, 0.f, 0.f};

#pragma unroll
    for (int kk = 0; kk < 4; kk++){
      bf16x8 bfr[4];
#pragma unroll
      for (int ctl = 0; ctl < 4; ctl++){
        int row = (wave*4 + ctl)*16 + n;
        bfr[ctl] = *(const bf16x8*)(Wcat + row*FDIM + kk*32 + q*8);
      }
      bf16x8 afr[4];
#pragma unroll
      for (int rt = 0; rt < 4; rt++){
        int r = rt*16 + n;
        int c16 = (kk*4 + q) ^ n;
        afr[rt] = *(const bf16x8*)(lds + r*FDIM + c16*8);
      }
#pragma unroll
      for (int rt = 0; rt < 4; rt++)
#pragma unroll
        for (int ctl = 0; ctl < 4; ctl++)
          acc[rt][ctl] = __builtin_amdgcn_mfma_f32_16x16x32_bf16(
              afr[rt], bfr[ctl], acc[rt][ctl], 0, 0, 0);
    }

    unsigned short* dstb = (wave < 2) ? Z : S;
    int s0 = 64*(wave & 1) + n*4;
#pragma unroll
    for (int rt = 0; rt < 4; rt++){
#pragma unroll
      for (int r = 0; r < 4; r++){
        int grow = row0 + rt*16 + q*4 + r;
        if (grow < N){
          float v0 = acc[rt][0][r] + bias[0];
          float v1 = acc[rt][1][r] + bias[1];
          float v2 = acc[rt][2][r] + bias[2];
          float v3 = acc[rt][3][r] + bias[3];
          u32x2 u;
          u[0] = ((unsigned)f2bf(v1) << 16) | (unsigned)f2bf(v0);
          u[1] = ((unsigned)f2bf(v3) << 16) | (unsigned)f2bf(v2);
          u32x2* dp = (u32x2*)(dstb + (size_t)grow*FDIM + s0);
          if (wave < 2) *dp = u;                         // Z: cached (gathered next)
          else __builtin_nontemporal_store(u, dp);       // S: stream
        }
      }
    }
  }
}

// ---------------- NEW: layer-1 aggregate only (un-fused, zero-LDS) ----------------
// R14: R1 showed achieved gather BW scales ~linearly with resident waves
// (33% occ -> 3.9 TB/s vs 17% -> 2.1). The fused kernel couldn't get waves
// (needs MFMA regs + LDS). This kernel: one 16-lane group per node, 8-deep
// uint4 gathers, no LDS, no MFMA, minimal registers -> high occupancy.
// h = relu(mean(Z[src]) + S) written IN PLACE over S (own row only).
__global__ __launch_bounds__(256)
void k_agg1(const unsigned short* __restrict__ Z, unsigned short* __restrict__ S,
            const int* __restrict__ row_off, const int* __restrict__ cnt,
            const int* __restrict__ csr_src, int N){
  const int tid   = threadIdx.x;
  const int node  = blockIdx.x*16 + (tid >> 4);
  const int g16   = tid & 15;
  const int gbase = (tid & 63) & 48;
  if (node >= N) return;
  int ro   = row_off[node];
  int deg  = cnt[node];
  int pdeg = (deg + 7) & ~7;
  float inv = 1.0f / (float)(deg > 1 ? deg : 1);
  float hacc[8];
#pragma unroll
  for (int z = 0; z < 8; z++) hacc[z] = 0.f;

  for (int base = 0; base < pdeg; base += 16){
    int rem = pdeg - base;
    int sidx = (g16 < rem) ? csr_src[ro + base + g16] : N;   // pad/dummy -> zero row
    {
      uint4 v[8];
#pragma unroll
      for (int t = 0; t < 8; t++){
        int id = __shfl(sidx, gbase + t);
        v[t] = *(const uint4*)(Z + (size_t)(unsigned)id*FDIM + g16*8);
      }
#pragma unroll
      for (int t = 0; t < 8; t++){
        hacc[0] += __uint_as_float(v[t].x << 16);
        hacc[1] += __uint_as_float(v[t].x & 0xFFFF0000u);
        hacc[2] += __uint_as_float(v[t].y << 16);
        hacc[3] += __uint_as_float(v[t].y & 0xFFFF0000u);
        hacc[4] += __uint_as_float(v[t].z << 16);
        hacc[5] += __uint_as_float(v[t].z & 0xFFFF0000u);
        hacc[6] += __uint_as_float(v[t].w << 16);
        hacc[7] += __uint_as_float(v[t].w & 0xFFFF0000u);
      }
    }
    if (rem > 8){
      uint4 v[8];
#pragma unroll
      for (int t = 0; t < 8; t++){
        int id = __shfl(sidx, gbase + 8 + t);
        v[t] = *(const uint4*)(Z + (size_t)(unsigned)id*FDIM + g16*8);
      }
#pragma unroll
      for (int t = 0; t < 8; t++){
        hacc[0] += __uint_as_float(v[t].x << 16);
        hacc[1] += __uint_as_float(v[t].x & 0xFFFF0000u);
        hacc[2] += __uint_as_float(v[t].y << 16);
        hacc[3] += __uint_as_float(v[t].y & 0xFFFF0000u);
        hacc[4] += __uint_as_float(v[t].z << 16);
        hacc[5] += __uint_as_float(v[t].z & 0xFFFF0000u);
        hacc[6] += __uint_as_float(v[t].w << 16);
        hacc[7] += __uint_as_float(v[t].w & 0xFFFF0000u);
      }
    }
  }

  u32x4 sv = __builtin_nontemporal_load((const u32x4*)(S + (size_t)node*FDIM + g16*8));
  bf16x8 p;
  p[0] = (short)f2bf(fmaxf(hacc[0]*inv + __uint_as_float(sv[0] << 16),          0.f));
  p[1] = (short)f2bf(fmaxf(hacc[1]*inv + __uint_as_float(sv[0] & 0xFFFF0000u),  0.f));
  p[2] = (short)f2bf(fmaxf(hacc[2]*inv + __uint_as_float(sv[1] << 16),          0.f));
  p[3] = (short)f2bf(fmaxf(hacc[3]*inv + __uint_as_float(sv[1] & 0xFFFF0000u),  0.f));
  p[4] = (short)f2bf(fmaxf(hacc[4]*inv + __uint_as_float(sv[2] << 16),          0.f));
  p[5] = (short)f2bf(fmaxf(hacc[5]*inv + __uint_as_float(sv[2] & 0xFFFF0000u),  0.f));
  p[6] = (short)f2bf(fmaxf(hacc[6]*inv + __uint_as_float(sv[3] << 16),          0.f));
  p[7] = (short)f2bf(fmaxf(hacc[7]*inv + __uint_as_float(sv[3] & 0xFFFF0000u),  0.f));
  *(bf16x8*)(S + (size_t)node*FDIM + g16*8) = p;   // h (cached: read by k_gemm2)
}

// ---------------- NEW: layer-2 dual GEMM on bf16 h (streaming) ----------------
// Input H = S buffer (permuted bf16 h). Z2 = h@Wl1^T (cached stores: next
// gather table, R13 lesson); S2 = h@Wr1^T + bias, in place over S (NT).
// Row-disjoint across blocks; read-before-write within block (barriered).
__global__ __launch_bounds__(256, 2)
void k_gemm2(const unsigned short* __restrict__ H, const unsigned short* __restrict__ Wcat,
             const float* __restrict__ bl, const float* __restrict__ br,
             unsigned short* __restrict__ Z2, unsigned short* __restrict__ S,
             int N, int nrb){
  __shared__ unsigned short lds[64*FDIM];
  const int tid  = threadIdx.x;
  const int wave = tid >> 6;
  const int lane = tid & 63;
  const int n = lane & 15, q = lane >> 4;

  float bias[4];
#pragma unroll
  for (int ctl = 0; ctl < 4; ctl++){
    int ct = wave*4 + ctl;
    if (ct >= 8){ int col = (ct - 8)*16 + n; bias[ctl] = bl[col] + br[col]; }
    else bias[ctl] = 0.0f;
  }

  u32x4 pf[4];
  const int r_   = tid >> 4;
  const int c16_ = tid & 15;

  auto issue_load = [&](int rb){
    int row0 = rb*64;
#pragma unroll
    for (int it = 0; it < 4; it++){
      int gr = row0 + r_ + it*16;
      if (gr < N)
        pf[it] = __builtin_nontemporal_load((const u32x4*)(H + (size_t)gr*FDIM + c16_*8));
      else
        pf[it] = (u32x4){0u,0u,0u,0u};
    }
  };

  int rb = blockIdx.x;
  if (rb < nrb) issue_load(rb);

  for (; rb < nrb; rb += gridDim.x){
    int row0 = rb*64;
    __syncthreads();
#pragma unroll
    for (int it = 0; it < 4; it++){
      int r = r_ + it*16;
      *(u32x4*)(lds + r*FDIM + ((c16_ ^ (r & 15)) * 8)) = pf[it];
    }
    __syncthreads();

    int rbn = rb + gridDim.x;
    if (rbn < nrb) issue_load(rbn);

    f32x4 acc[4][4];
#pragma unroll
    for (int rt = 0; rt < 4; rt++)
#pragma unroll
      for (int ctl = 0; ctl < 4; ctl++)
        acc[rt][ctl] = (f32x4){0.f, 0.f, 0.f, 0.f};

#pragma unroll
    for (int kk = 0; kk < 4; kk++){
      bf16x8 bfr[4];
#pragma unroll
      for (int ctl = 0; ctl < 4; ctl++){
        int row = (wave*4 + ctl)*16 + n;
        bfr[ctl] = *(const bf16x8*)(Wcat + row*FDIM + kk*32 + q*8);
      }
      bf16x8 afr[4];
#pragma unroll
      for (int rt = 0; rt < 4; rt++){
        int r = rt*16 + n;
        int c16 = (kk*4 + q) ^ n;
        afr[rt] = *(const bf16x8*)(lds + r*FDIM + c16*8);
      }
#pragma unroll
      for (int rt = 0; rt < 4; rt++)
#pragma unroll
        for (int ctl = 0; ctl < 4; ctl++)
          acc[rt][ctl] = __builtin_amdgcn_mfma_f32_16x16x32_bf16(
              afr[rt], bfr[ctl], acc[rt][ctl], 0, 0, 0);
    }

    unsigned short* dstb = (wave < 2) ? Z2 : S;
    int s0c = 64*(wave & 1) + n*4;
#pragma unroll
    for (int rt = 0; rt < 4; rt++){
#pragma unroll
      for (int r = 0; r < 4; r++){
        int grow = row0 + rt*16 + q*4 + r;
        if (grow < N){
          float v0 = acc[rt][0][r] + bias[0];
          float v1 = acc[rt][1][r] + bias[1];
          float v2 = acc[rt][2][r] + bias[2];
          float v3 = acc[rt][3][r] + bias[3];
          u32x2 u;
          u[0] = ((unsigned)f2bf(v1) << 16) | (unsigned)f2bf(v0);
          u[1] = ((unsigned)f2bf(v3) << 16) | (unsigned)f2bf(v2);
          u32x2* dp = (u32x2*)(dstb + (size_t)grow*FDIM + s0c);
          if (wave < 2) *dp = u;                         // Z2: cached
          else __builtin_nontemporal_store(u, dp);       // S2: stream
        }
      }
    }
  }
}

// ---------------- final aggregate: out = relu(sum(Z2[src])/deg + S2) ----------------
// R14: same zero-LDS group-per-node shape as k_agg1 for high occupancy.
// Un-permute via per-element scattered stores (R4 showed LDS-coalescing
// the output was worth ~0).
__global__ __launch_bounds__(256)
void k_aggregate(const unsigned short* __restrict__ Z2, const unsigned short* __restrict__ S,
                 const int* __restrict__ row_off, const int* __restrict__ cnt,
                 const int* __restrict__ csr_src, float* __restrict__ Out, int N){
  const int tid   = threadIdx.x;
  const int node  = blockIdx.x*16 + (tid >> 4);
  const int g16   = tid & 15;
  const int gbase = (tid & 63) & 48;
  if (node >= N) return;
  int ro   = row_off[node];
  int deg  = cnt[node];
  int pdeg = (deg + 7) & ~7;
  float inv = 1.0f / (float)(deg > 1 ? deg : 1);
  float hacc[8];
#pragma unroll
  for (int z = 0; z < 8; z++) hacc[z] = 0.f;

  for (int base = 0; base < pdeg; base += 16){
    int rem = pdeg - base;
    int sidx = (g16 < rem) ? csr_src[ro + base + g16] : N;
    {
      uint4 v[8];
#pragma unroll
      for (int t = 0; t < 8; t++){
        int id = __shfl(sidx, gbase + t);
        v[t] = *(const uint4*)(Z2 + (size_t)(unsigned)id*FDIM + g16*8);
      }
#pragma unroll
      for (int t = 0; t < 8; t++){
        hacc[0] += __uint_as_float(v[t].x << 16);
        hacc[1] += __uint_as_float(v[t].x & 0xFFFF0000u);
        hacc[2] += __uint_as_float(v[t].y << 16);
        hacc[3] += __uint_as_float(v[t].y & 0xFFFF0000u);
        hacc[4] += __uint_as_float(v[t].z << 16);
        hacc[5] += __uint_as_float(v[t].z & 0xFFFF0000u);
        hacc[6] += __uint_as_float(v[t].w << 16);
        hacc[7] += __uint_as_float(v[t].w & 0xFFFF0000u);
      }
    }
    if (rem > 8){
      uint4 v[8];
#pragma unroll
      for (int t = 0; t < 8; t++){
        int id = __shfl(sidx, gbase + 8 + t);
        v[t] = *(const uint4*)(Z2 + (size_t)(unsigned)id*FDIM + g16*8);
      }
#pragma unroll
      for (int t = 0; t < 8; t++){
        hacc[0] += __uint_as_float(v[t].x << 16);
        hacc[1] += __uint_as_float(v[t].x & 0xFFFF0000u);
        hacc[2] += __uint_as_float(v[t].y << 16);
        hacc[3] += __uint_as_float(v[t].y & 0xFFFF0000u);
        hacc[4] += __uint_as_float(v[t].z << 16);
        hacc[5] += __uint_as_float(v[t].z & 0xFFFF0000u);
        hacc[6] += __uint_as_float(v[t].w << 16);
        hacc[7] += __uint_as_float(v[t].w & 0xFFFF0000u);
      }
    }
  }

  u32x4 sv = __builtin_nontemporal_load((const u32x4*)(S + (size_t)node*FDIM + g16*8));
  float o[8];
  o[0] = fmaxf(hacc[0]*inv + __uint_as_float(sv[0] << 16),          0.f);
  o[1] = fmaxf(hacc[1]*inv + __uint_as_float(sv[0] & 0xFFFF0000u),  0.f);
  o[2] = fmaxf(hacc[2]*inv + __uint_as_float(sv[1] << 16),          0.f);
  o[3] = fmaxf(hacc[3]*inv + __uint_as_float(sv[1] & 0xFFFF0000u),  0.f);
  o[4] = fmaxf(hacc[4]*inv + __uint_as_float(sv[2] << 16),          0.f);
  o[5] = fmaxf(hacc[5]*inv + __uint_as_float(sv[2] & 0xFFFF0000u),  0.f);
  o[6] = fmaxf(hacc[6]*inv + __uint_as_float(sv[3] << 16),          0.f);
  o[7] = fmaxf(hacc[7]*inv + __uint_as_float(sv[3] & 0xFFFF0000u),  0.f);
  // un-permute: stored s = g16*8+z -> orig c; scattered 4B NT stores
#pragma unroll
  for (int z = 0; z < 8; z++){
    int s_ = g16*8 + z;
    int hi = s_ >> 6, s6 = s_ & 63;
    int c = ((s6 & 3) + 4*hi)*16 + (s6 >> 2);
    __builtin_nontemporal_store(o[z], Out + (size_t)node*FDIM + c);
  }
}

extern "C" void kernel_launch(void* const* d_in, const int* in_sizes, int n_in,
                              void* d_out, int out_size, void* d_ws, size_t ws_size,
                              hipStream_t stream){
  const float* x   = (const float*)d_in[0];
  const int*   eix = (const int*)d_in[1];
  const float* Wl0 = (const float*)d_in[2];
  const float* bl0 = (const float*)d_in[3];
  const float* Wr0 = (const float*)d_in[4];
  const float* br0 = (const float*)d_in[5];
  const float* Wl1 = (const float*)d_in[6];
  const float* bl1 = (const float*)d_in[7];
  const float* Wr1 = (const float*)d_in[8];
  const float* br1 = (const float*)d_in[9];
  float* out = (float*)d_out;

  int N = in_sizes[0] / FDIM;
  int E = in_sizes[1] / 2;
  const int* src = eix;
  const int* dst = eix + E;

  // workspace (Z and Z2 have N+1 rows: row N is the zero dummy row)
  unsigned short* Z    = (unsigned short*)d_ws;
  unsigned short* Z2   = Z  + (size_t)(N + 1)*FDIM;
  unsigned short* S    = Z2 + (size_t)(N + 1)*FDIM;
  unsigned short* Wcat = S  + (size_t)N*FDIM;
  int* cnt     = (int*)(Wcat + 2*256*128);
  int* row_off = cnt + N;
  int* cursor  = row_off + N;
  int* csr_src = cursor + N;                 // capacity: E + 7N (padding bound)
  int* partials= csr_src + (E + 7*N);

  int nb = (N + 255)/256;

  k_init         <<<nb + 256, 256, 0, stream>>>(Wl0, Wr0, Wl1, Wr1, Wcat, cnt,
                                                Z + (size_t)N*FDIM, Z2 + (size_t)N*FDIM, N, nb);
  k_degree       <<<(E + 255)/256, 256, 0, stream>>>(dst, cnt, E);
  k_scan_blocks  <<<nb, 256, 0, stream>>>(cnt, row_off, partials, N);
  k_scan_partials<<<1, 512, 0, stream>>>(partials, nb);
  k_finalize_pad <<<nb, 256, 0, stream>>>(row_off, partials, cursor, cnt, csr_src, N);
  k_fill         <<<(E + 255)/256, 256, 0, stream>>>(src, dst, cursor, csr_src, E);

  int nrb  = (N + 63)/64;
  int ngrp = (N + 15)/16;
  k_dualgemm1<<<512, 256, 0, stream>>>(x, Wcat, bl0, br0, Z, S, N, nrb);
  k_agg1     <<<ngrp, 256, 0, stream>>>(Z, S, row_off, cnt, csr_src, N);
  k_gemm2    <<<512, 256, 0, stream>>>(S, Wcat + 256*128, bl1, br1, Z2, S, N, nrb);
  k_aggregate<<<ngrp, 256, 0, stream>>>(Z2, S, row_off, cnt, csr_src, out, N);
}

// Round 10
// 266.296 us; speedup vs baseline: 1.1316x; 1.0092x over previous
//
#include <hip/hip_runtime.h>

#define FDIM 128

typedef __attribute__((ext_vector_type(8))) short bf16x8;
typedef __attribute__((ext_vector_type(4))) float f32x4;
typedef __attribute__((ext_vector_type(2))) float f32x2;
typedef __attribute__((ext_vector_type(4))) unsigned int u32x4;
typedef __attribute__((ext_vector_type(2))) unsigned int u32x2;

// Column permutation for internal Z/S storage (within a 128-col half):
//   orig c: ct=c>>4, n=c&15  ->  stored s = 64*(ct>=4) + n*4 + (ct&3)
//   inv:    hi=s>>6, s6=s&63, n=s6>>2, ctl=s6&3 -> c = (ctl+4*hi)*16 + n

__device__ __forceinline__ unsigned short f2bf(float f){
  unsigned int u = __float_as_uint(f);
  unsigned int r = u + 0x7FFFu + ((u >> 16) & 1u);
  return (unsigned short)(r >> 16);
}

// ---------------- init: zero cnt, zero dummy Z/Z2 rows, build Wcat ----------------
__global__ void k_init(const float* __restrict__ Wl0, const float* __restrict__ Wr0,
                       const float* __restrict__ Wl1, const float* __restrict__ Wr1,
                       unsigned short* __restrict__ Wcat, int* __restrict__ cnt,
                       unsigned short* __restrict__ Zdummy, unsigned short* __restrict__ Z2dummy,
                       int N, int nb){
  int b = blockIdx.x;
  if (b < nb){
    int i = b*256 + threadIdx.x;
    if (i < N) cnt[i] = 0;
    if (b == 0 && threadIdx.x < FDIM){
      Zdummy[threadIdx.x]  = 0;
      Z2dummy[threadIdx.x] = 0;
    }
  } else {
    int i = (b - nb)*256 + threadIdx.x;     // 0 .. 65535
    int l   = i >> 15;
    int rem = i & 32767;
    int row = rem >> 7, k = rem & 127;
    int ksrc = k;
    if (l == 1){
      int hi = k >> 6, s6 = k & 63;
      ksrc = ((s6 & 3) + 4*hi)*16 + (s6 >> 2);   // invPerm(k)
    }
    const float* W = (l == 0) ? ((row < 128) ? Wl0 : Wr0)
                              : ((row < 128) ? Wl1 : Wr1);
    Wcat[i] = f2bf(W[(row & 127)*128 + ksrc]);
  }
}

// ---------------- degree ----------------
__global__ void k_degree(const int* __restrict__ dst, int* __restrict__ cnt, int E){
  int e = blockIdx.x*256 + threadIdx.x;
  if (e < E) atomicAdd(&cnt[dst[e]], 1);
}

// ---------------- hierarchical scan over PADDED degrees ----------------
__global__ void k_scan_blocks(const int* __restrict__ cnt, int* __restrict__ excl,
                              int* __restrict__ partials, int N){
  __shared__ int s[256];
  int tid = threadIdx.x;
  int i = blockIdx.x*256 + tid;
  int v = (i < N) ? ((cnt[i] + 7) & ~7) : 0;
  s[tid] = v; __syncthreads();
  for (int off = 1; off < 256; off <<= 1){
    int t = (tid >= off) ? s[tid - off] : 0;
    __syncthreads();
    s[tid] += t;
    __syncthreads();
  }
  if (i < N) excl[i] = s[tid] - v;
  if (tid == 255) partials[blockIdx.x] = s[255];
}

__global__ void k_scan_partials(int* __restrict__ partials, int nb){
  __shared__ int s[512];
  int tid = threadIdx.x;
  int v = (tid < nb) ? partials[tid] : 0;
  s[tid] = v; __syncthreads();
  for (int off = 1; off < 512; off <<= 1){
    int t = (tid >= off) ? s[tid - off] : 0;
    __syncthreads();
    s[tid] += t;
    __syncthreads();
  }
  if (tid < nb) partials[tid] = s[tid] - v;
}

// finalize + pad fused (pad writes slots >= deg, fill writes < deg: disjoint)
__global__ void k_finalize_pad(int* __restrict__ row_off, const int* __restrict__ partials,
                               int* __restrict__ cursor, const int* __restrict__ cnt,
                               int* __restrict__ csr_src, int N){
  int i = blockIdx.x*256 + threadIdx.x;
  if (i >= N) return;
  int ro = row_off[i] + partials[blockIdx.x];
  row_off[i] = ro;
  cursor[i]  = ro;
  int d  = cnt[i];
  int pd = (d + 7) & ~7;
  for (int p = d; p < pd; p++) csr_src[ro + p] = N;
}

// ---------------- fill ----------------
__global__ void k_fill(const int* __restrict__ src, const int* __restrict__ dst,
                       int* __restrict__ cursor, int* __restrict__ csr_src, int E){
  int e = blockIdx.x*256 + threadIdx.x;
  if (e >= E) return;
  int d = dst[e];
  int pos = atomicAdd(&cursor[d], 1);
  csr_src[pos] = src[e];
}

// ---------------- layer-1 dual GEMM: Z = X@Wl^T, S = X@Wr^T + (bl+br) ----------------
// R13 config: grid 512, (256,2); X cached, S stores NT, Z stores cached.
__global__ __launch_bounds__(256, 2)
void k_dualgemm1(const float* __restrict__ X, const unsigned short* __restrict__ Wcat,
                 const float* __restrict__ bl, const float* __restrict__ br,
                 unsigned short* __restrict__ Z, unsigned short* __restrict__ S,
                 int N, int nrb){
  __shared__ unsigned short lds[64*FDIM];
  const int tid  = threadIdx.x;
  const int wave = tid >> 6;
  const int lane = tid & 63;
  const int n = lane & 15, q = lane >> 4;

  float bias[4];
#pragma unroll
  for (int ctl = 0; ctl < 4; ctl++){
    int ct = wave*4 + ctl;
    if (ct >= 8){ int col = (ct - 8)*16 + n; bias[ctl] = bl[col] + br[col]; }
    else bias[ctl] = 0.0f;
  }

  f32x4 pf[8];
  const int r_   = tid >> 4;
  const int c16_ = tid & 15;

  auto issue_load = [&](int rb){
    int row0 = rb*64;
#pragma unroll
    for (int it = 0; it < 4; it++){
      int r  = r_ + it*16;
      int gr = row0 + r;
      if (gr < N){
        const f32x4* sp = (const f32x4*)(X + (size_t)gr*FDIM + c16_*8);
        pf[2*it]   = sp[0];
        pf[2*it+1] = sp[1];
      } else {
        pf[2*it]   = (f32x4){0.f,0.f,0.f,0.f};
        pf[2*it+1] = (f32x4){0.f,0.f,0.f,0.f};
      }
    }
  };

  int rb = blockIdx.x;
  if (rb < nrb) issue_load(rb);

  for (; rb < nrb; rb += gridDim.x){
    int row0 = rb*64;
    __syncthreads();
#pragma unroll
    for (int it = 0; it < 4; it++){
      int r = r_ + it*16;
      f32x4 v0 = pf[2*it], v1 = pf[2*it+1];
      bf16x8 p;
      p[0] = (short)f2bf(v0[0]); p[1] = (short)f2bf(v0[1]);
      p[2] = (short)f2bf(v0[2]); p[3] = (short)f2bf(v0[3]);
      p[4] = (short)f2bf(v1[0]); p[5] = (short)f2bf(v1[1]);
      p[6] = (short)f2bf(v1[2]); p[7] = (short)f2bf(v1[3]);
      *(bf16x8*)(lds + r*FDIM + ((c16_ ^ (r & 15)) * 8)) = p;
    }
    __syncthreads();

    int rbn = rb + gridDim.x;
    if (rbn < nrb) issue_load(rbn);

    f32x4 acc[4][4];
#pragma unroll
    for (int rt = 0; rt < 4; rt++)
#pragma unroll
      for (int ctl = 0; ctl < 4; ctl++)
        acc[rt][ctl] = (f32x4){0.f, 0.f, 0.f, 0.f};

#pragma unroll
    for (int kk = 0; kk < 4; kk++){
      bf16x8 bfr[4];
#pragma unroll
      for (int ctl = 0; ctl < 4; ctl++){
        int row = (wave*4 + ctl)*16 + n;
        bfr[ctl] = *(const bf16x8*)(Wcat + row*FDIM + kk*32 + q*8);
      }
      bf16x8 afr[4];
#pragma unroll
      for (int rt = 0; rt < 4; rt++){
        int r = rt*16 + n;
        int c16 = (kk*4 + q) ^ n;
        afr[rt] = *(const bf16x8*)(lds + r*FDIM + c16*8);
      }
#pragma unroll
      for (int rt = 0; rt < 4; rt++)
#pragma unroll
        for (int ctl = 0; ctl < 4; ctl++)
          acc[rt][ctl] = __builtin_amdgcn_mfma_f32_16x16x32_bf16(
              afr[rt], bfr[ctl], acc[rt][ctl], 0, 0, 0);
    }

    unsigned short* dstb = (wave < 2) ? Z : S;
    int s0 = 64*(wave & 1) + n*4;
#pragma unroll
    for (int rt = 0; rt < 4; rt++){
#pragma unroll
      for (int r = 0; r < 4; r++){
        int grow = row0 + rt*16 + q*4 + r;
        if (grow < N){
          float v0 = acc[rt][0][r] + bias[0];
          float v1 = acc[rt][1][r] + bias[1];
          float v2 = acc[rt][2][r] + bias[2];
          float v3 = acc[rt][3][r] + bias[3];
          u32x2 u;
          u[0] = ((unsigned)f2bf(v1) << 16) | (unsigned)f2bf(v0);
          u[1] = ((unsigned)f2bf(v3) << 16) | (unsigned)f2bf(v2);
          u32x2* dp = (u32x2*)(dstb + (size_t)grow*FDIM + s0);
          if (wave < 2) *dp = u;                         // Z: cached (gathered next)
          else __builtin_nontemporal_store(u, dp);       // S: stream
        }
      }
    }
  }
}

// ---------------- layer-1 aggregate only (un-fused, zero-LDS; R14 win) ----------------
// h = relu(mean(Z[src]) + S) written IN PLACE over S (own row only).
__global__ __launch_bounds__(256)
void k_agg1(const unsigned short* __restrict__ Z, unsigned short* __restrict__ S,
            const int* __restrict__ row_off, const int* __restrict__ cnt,
            const int* __restrict__ csr_src, int N){
  const int tid   = threadIdx.x;
  const int node  = blockIdx.x*16 + (tid >> 4);
  const int g16   = tid & 15;
  const int gbase = (tid & 63) & 48;
  if (node >= N) return;
  int ro   = row_off[node];
  int deg  = cnt[node];
  int pdeg = (deg + 7) & ~7;
  float inv = 1.0f / (float)(deg > 1 ? deg : 1);
  float hacc[8];
#pragma unroll
  for (int z = 0; z < 8; z++) hacc[z] = 0.f;

  for (int base = 0; base < pdeg; base += 16){
    int rem = pdeg - base;
    int sidx = (g16 < rem) ? csr_src[ro + base + g16] : N;   // pad/dummy -> zero row
    {
      uint4 v[8];
#pragma unroll
      for (int t = 0; t < 8; t++){
        int id = __shfl(sidx, gbase + t);
        v[t] = *(const uint4*)(Z + (size_t)(unsigned)id*FDIM + g16*8);
      }
#pragma unroll
      for (int t = 0; t < 8; t++){
        hacc[0] += __uint_as_float(v[t].x << 16);
        hacc[1] += __uint_as_float(v[t].x & 0xFFFF0000u);
        hacc[2] += __uint_as_float(v[t].y << 16);
        hacc[3] += __uint_as_float(v[t].y & 0xFFFF0000u);
        hacc[4] += __uint_as_float(v[t].z << 16);
        hacc[5] += __uint_as_float(v[t].z & 0xFFFF0000u);
        hacc[6] += __uint_as_float(v[t].w << 16);
        hacc[7] += __uint_as_float(v[t].w & 0xFFFF0000u);
      }
    }
    if (rem > 8){
      uint4 v[8];
#pragma unroll
      for (int t = 0; t < 8; t++){
        int id = __shfl(sidx, gbase + 8 + t);
        v[t] = *(const uint4*)(Z + (size_t)(unsigned)id*FDIM + g16*8);
      }
#pragma unroll
      for (int t = 0; t < 8; t++){
        hacc[0] += __uint_as_float(v[t].x << 16);
        hacc[1] += __uint_as_float(v[t].x & 0xFFFF0000u);
        hacc[2] += __uint_as_float(v[t].y << 16);
        hacc[3] += __uint_as_float(v[t].y & 0xFFFF0000u);
        hacc[4] += __uint_as_float(v[t].z << 16);
        hacc[5] += __uint_as_float(v[t].z & 0xFFFF0000u);
        hacc[6] += __uint_as_float(v[t].w << 16);
        hacc[7] += __uint_as_float(v[t].w & 0xFFFF0000u);
      }
    }
  }

  u32x4 sv = __builtin_nontemporal_load((const u32x4*)(S + (size_t)node*FDIM + g16*8));
  bf16x8 p;
  p[0] = (short)f2bf(fmaxf(hacc[0]*inv + __uint_as_float(sv[0] << 16),          0.f));
  p[1] = (short)f2bf(fmaxf(hacc[1]*inv + __uint_as_float(sv[0] & 0xFFFF0000u),  0.f));
  p[2] = (short)f2bf(fmaxf(hacc[2]*inv + __uint_as_float(sv[1] << 16),          0.f));
  p[3] = (short)f2bf(fmaxf(hacc[3]*inv + __uint_as_float(sv[1] & 0xFFFF0000u),  0.f));
  p[4] = (short)f2bf(fmaxf(hacc[4]*inv + __uint_as_float(sv[2] << 16),          0.f));
  p[5] = (short)f2bf(fmaxf(hacc[5]*inv + __uint_as_float(sv[2] & 0xFFFF0000u),  0.f));
  p[6] = (short)f2bf(fmaxf(hacc[6]*inv + __uint_as_float(sv[3] << 16),          0.f));
  p[7] = (short)f2bf(fmaxf(hacc[7]*inv + __uint_as_float(sv[3] & 0xFFFF0000u),  0.f));
  *(bf16x8*)(S + (size_t)node*FDIM + g16*8) = p;   // h (cached: read by k_gemm2)
}

// ---------------- layer-2 dual GEMM on bf16 h (streaming) ----------------
// R15: H loads CACHED (h was just written cached by k_agg1 -> L2-hot; R9's
// NT hint forfeited those hits). Z2 stores cached (next gather table);
// S2 stores NT (stream).
__global__ __launch_bounds__(256, 2)
void k_gemm2(const unsigned short* __restrict__ H, const unsigned short* __restrict__ Wcat,
             const float* __restrict__ bl, const float* __restrict__ br,
             unsigned short* __restrict__ Z2, unsigned short* __restrict__ S,
             int N, int nrb){
  __shared__ unsigned short lds[64*FDIM];
  const int tid  = threadIdx.x;
  const int wave = tid >> 6;
  const int lane = tid & 63;
  const int n = lane & 15, q = lane >> 4;

  float bias[4];
#pragma unroll
  for (int ctl = 0; ctl < 4; ctl++){
    int ct = wave*4 + ctl;
    if (ct >= 8){ int col = (ct - 8)*16 + n; bias[ctl] = bl[col] + br[col]; }
    else bias[ctl] = 0.0f;
  }

  u32x4 pf[4];
  const int r_   = tid >> 4;
  const int c16_ = tid & 15;

  auto issue_load = [&](int rb){
    int row0 = rb*64;
#pragma unroll
    for (int it = 0; it < 4; it++){
      int gr = row0 + r_ + it*16;
      if (gr < N)
        pf[it] = *(const u32x4*)(H + (size_t)gr*FDIM + c16_*8);
      else
        pf[it] = (u32x4){0u,0u,0u,0u};
    }
  };

  int rb = blockIdx.x;
  if (rb < nrb) issue_load(rb);

  for (; rb < nrb; rb += gridDim.x){
    int row0 = rb*64;
    __syncthreads();
#pragma unroll
    for (int it = 0; it < 4; it++){
      int r = r_ + it*16;
      *(u32x4*)(lds + r*FDIM + ((c16_ ^ (r & 15)) * 8)) = pf[it];
    }
    __syncthreads();

    int rbn = rb + gridDim.x;
    if (rbn < nrb) issue_load(rbn);

    f32x4 acc[4][4];
#pragma unroll
    for (int rt = 0; rt < 4; rt++)
#pragma unroll
      for (int ctl = 0; ctl < 4; ctl++)
        acc[rt][ctl] = (f32x4){0.f, 0.f, 0.f, 0.f};

#pragma unroll
    for (int kk = 0; kk < 4; kk++){
      bf16x8 bfr[4];
#pragma unroll
      for (int ctl = 0; ctl < 4; ctl++){
        int row = (wave*4 + ctl)*16 + n;
        bfr[ctl] = *(const bf16x8*)(Wcat + row*FDIM + kk*32 + q*8);
      }
      bf16x8 afr[4];
#pragma unroll
      for (int rt = 0; rt < 4; rt++){
        int r = rt*16 + n;
        int c16 = (kk*4 + q) ^ n;
        afr[rt] = *(const bf16x8*)(lds + r*FDIM + c16*8);
      }
#pragma unroll
      for (int rt = 0; rt < 4; rt++)
#pragma unroll
        for (int ctl = 0; ctl < 4; ctl++)
          acc[rt][ctl] = __builtin_amdgcn_mfma_f32_16x16x32_bf16(
              afr[rt], bfr[ctl], acc[rt][ctl], 0, 0, 0);
    }

    unsigned short* dstb = (wave < 2) ? Z2 : S;
    int s0c = 64*(wave & 1) + n*4;
#pragma unroll
    for (int rt = 0; rt < 4; rt++){
#pragma unroll
      for (int r = 0; r < 4; r++){
        int grow = row0 + rt*16 + q*4 + r;
        if (grow < N){
          float v0 = acc[rt][0][r] + bias[0];
          float v1 = acc[rt][1][r] + bias[1];
          float v2 = acc[rt][2][r] + bias[2];
          float v3 = acc[rt][3][r] + bias[3];
          u32x2 u;
          u[0] = ((unsigned)f2bf(v1) << 16) | (unsigned)f2bf(v0);
          u[1] = ((unsigned)f2bf(v3) << 16) | (unsigned)f2bf(v2);
          u32x2* dp = (u32x2*)(dstb + (size_t)grow*FDIM + s0c);
          if (wave < 2) *dp = u;                         // Z2: cached
          else __builtin_nontemporal_store(u, dp);       // S2: stream
        }
      }
    }
  }
}

// ---------------- final aggregate: out = relu(sum(Z2[src])/deg + S2) ----------------
// Zero-LDS group-per-node shape. R15: un-permute algebra gives paired columns
// — c = (z&3)*16 + (z>>2) + base, base = 64*(g16>>3) + (g16&7)*2 — so the 8
// scalar 4B stores collapse to 4 aligned float2 stores, each offset covering
// two contiguous 64B segments per 16-lane group.
__global__ __launch_bounds__(256)
void k_aggregate(const unsigned short* __restrict__ Z2, const unsigned short* __restrict__ S,
                 const int* __restrict__ row_off, const int* __restrict__ cnt,
                 const int* __restrict__ csr_src, float* __restrict__ Out, int N){
  const int tid   = threadIdx.x;
  const int node  = blockIdx.x*16 + (tid >> 4);
  const int g16   = tid & 15;
  const int gbase = (tid & 63) & 48;
  if (node >= N) return;
  int ro   = row_off[node];
  int deg  = cnt[node];
  int pdeg = (deg + 7) & ~7;
  float inv = 1.0f / (float)(deg > 1 ? deg : 1);
  float hacc[8];
#pragma unroll
  for (int z = 0; z < 8; z++) hacc[z] = 0.f;

  for (int base = 0; base < pdeg; base += 16){
    int rem = pdeg - base;
    int sidx = (g16 < rem) ? csr_src[ro + base + g16] : N;
    {
      uint4 v[8];
#pragma unroll
      for (int t = 0; t < 8; t++){
        int id = __shfl(sidx, gbase + t);
        v[t] = *(const uint4*)(Z2 + (size_t)(unsigned)id*FDIM + g16*8);
      }
#pragma unroll
      for (int t = 0; t < 8; t++){
        hacc[0] += __uint_as_float(v[t].x << 16);
        hacc[1] += __uint_as_float(v[t].x & 0xFFFF0000u);
        hacc[2] += __uint_as_float(v[t].y << 16);
        hacc[3] += __uint_as_float(v[t].y & 0xFFFF0000u);
        hacc[4] += __uint_as_float(v[t].z << 16);
        hacc[5] += __uint_as_float(v[t].z & 0xFFFF0000u);
        hacc[6] += __uint_as_float(v[t].w << 16);
        hacc[7] += __uint_as_float(v[t].w & 0xFFFF0000u);
      }
    }
    if (rem > 8){
      uint4 v[8];
#pragma unroll
      for (int t = 0; t < 8; t++){
        int id = __shfl(sidx, gbase + 8 + t);
        v[t] = *(const uint4*)(Z2 + (size_t)(unsigned)id*FDIM + g16*8);
      }
#pragma unroll
      for (int t = 0; t < 8; t++){
        hacc[0] += __uint_as_float(v[t].x << 16);
        hacc[1] += __uint_as_float(v[t].x & 0xFFFF0000u);
        hacc[2] += __uint_as_float(v[t].y << 16);
        hacc[3] += __uint_as_float(v[t].y & 0xFFFF0000u);
        hacc[4] += __uint_as_float(v[t].z << 16);
        hacc[5] += __uint_as_float(v[t].z & 0xFFFF0000u);
        hacc[6] += __uint_as_float(v[t].w << 16);
        hacc[7] += __uint_as_float(v[t].w & 0xFFFF0000u);
      }
    }
  }

  u32x4 sv = __builtin_nontemporal_load((const u32x4*)(S + (size_t)node*FDIM + g16*8));
  float o[8];
  o[0] = fmaxf(hacc[0]*inv + __uint_as_float(sv[0] << 16),          0.f);
  o[1] = fmaxf(hacc[1]*inv + __uint_as_float(sv[0] & 0xFFFF0000u),  0.f);
  o[2] = fmaxf(hacc[2]*inv + __uint_as_float(sv[1] << 16),          0.f);
  o[3] = fmaxf(hacc[3]*inv + __uint_as_float(sv[1] & 0xFFFF0000u),  0.f);
  o[4] = fmaxf(hacc[4]*inv + __uint_as_float(sv[2] << 16),          0.f);
  o[5] = fmaxf(hacc[5]*inv + __uint_as_float(sv[2] & 0xFFFF0000u),  0.f);
  o[6] = fmaxf(hacc[6]*inv + __uint_as_float(sv[3] << 16),          0.f);
  o[7] = fmaxf(hacc[7]*inv + __uint_as_float(sv[3] & 0xFFFF0000u),  0.f);
  // un-permute via paired float2 stores: pair k = (o[k], o[k+4]) at base + k*16
  int obase = 64*(g16 >> 3) + (g16 & 7)*2;
#pragma unroll
  for (int k = 0; k < 4; k++){
    f32x2 w; w[0] = o[k]; w[1] = o[k+4];
    __builtin_nontemporal_store(w, (f32x2*)(Out + (size_t)node*FDIM + obase + k*16));
  }
}

extern "C" void kernel_launch(void* const* d_in, const int* in_sizes, int n_in,
                              void* d_out, int out_size, void* d_ws, size_t ws_size,
                              hipStream_t stream){
  const float* x   = (const float*)d_in[0];
  const int*   eix = (const int*)d_in[1];
  const float* Wl0 = (const float*)d_in[2];
  const float* bl0 = (const float*)d_in[3];
  const float* Wr0 = (const float*)d_in[4];
  const float* br0 = (const float*)d_in[5];
  const float* Wl1 = (const float*)d_in[6];
  const float* bl1 = (const float*)d_in[7];
  const float* Wr1 = (const float*)d_in[8];
  const float* br1 = (const float*)d_in[9];
  float* out = (float*)d_out;

  int N = in_sizes[0] / FDIM;
  int E = in_sizes[1] / 2;
  const int* src = eix;
  const int* dst = eix + E;

  // workspace (Z and Z2 have N+1 rows: row N is the zero dummy row)
  unsigned short* Z    = (unsigned short*)d_ws;
  unsigned short* Z2   = Z  + (size_t)(N + 1)*FDIM;
  unsigned short* S    = Z2 + (size_t)(N + 1)*FDIM;
  unsigned short* Wcat = S  + (size_t)N*FDIM;
  int* cnt     = (int*)(Wcat + 2*256*128);
  int* row_off = cnt + N;
  int* cursor  = row_off + N;
  int* csr_src = cursor + N;                 // capacity: E + 7N (padding bound)
  int* partials= csr_src + (E + 7*N);

  int nb = (N + 255)/256;

  k_init         <<<nb + 256, 256, 0, stream>>>(Wl0, Wr0, Wl1, Wr1, Wcat, cnt,
                                                Z + (size_t)N*FDIM, Z2 + (size_t)N*FDIM, N, nb);
  k_degree       <<<(E + 255)/256, 256, 0, stream>>>(dst, cnt, E);
  k_scan_blocks  <<<nb, 256, 0, stream>>>(cnt, row_off, partials, N);
  k_scan_partials<<<1, 512, 0, stream>>>(partials, nb);
  k_finalize_pad <<<nb, 256, 0, stream>>>(row_off, partials, cursor, cnt, csr_src, N);
  k_fill         <<<(E + 255)/256, 256, 0, stream>>>(src, dst, cursor, csr_src, E);

  int nrb  = (N + 63)/64;
  int ngrp = (N + 15)/16;
  k_dualgemm1<<<512, 256, 0, stream>>>(x, Wcat, bl0, br0, Z, S, N, nrb);
  k_agg1     <<<ngrp, 256, 0, stream>>>(Z, S, row_off, cnt, csr_src, N);
  k_gemm2    <<<512, 256, 0, stream>>>(S, Wcat + 256*128, bl1, br1, Z2, S, N, nrb);
  k_aggregate<<<ngrp, 256, 0, stream>>>(Z2, S, row_off, cnt, csr_src, out, N);
}